// Round 8
// baseline (917.491 us; speedup 1.0000x reference)
//
#include <hip/hip_runtime.h>
#include <cfloat>

#define N_NODES 50000
#define N_EDGES 800000
#define E_TOT   850000
#define NG      128
#define NH      4

typedef float f4 __attribute__((ext_vector_type(4)));
typedef _Float16 h2v __attribute__((ext_vector_type(2)));
typedef _Float16 h4v __attribute__((ext_vector_type(4)));
typedef _Float16 h8v __attribute__((ext_vector_type(8)));

// ---------------- CSR build (by destination) ----------------
__global__ void count_dst_k(const int* __restrict__ ei, int* __restrict__ cnt) {
    int e = blockIdx.x * blockDim.x + threadIdx.x;
    if (e >= E_TOT) return;
    int d = (e < N_EDGES) ? ei[N_EDGES + e] : (e - N_EDGES);
    atomicAdd(&cnt[d], 1);
}

__global__ void scan_k(const int* __restrict__ cnt, int* __restrict__ row_ptr,
                       int* __restrict__ cursor) {
    __shared__ int wsum[16];
    __shared__ int carry_sh;
    int lane = threadIdx.x & 63, wv = threadIdx.x >> 6;
    if (threadIdx.x == 0) carry_sh = 0;
    __syncthreads();
    for (int base = 0; base < N_NODES; base += 1024) {
        int i = base + threadIdx.x;
        int v = (i < N_NODES) ? cnt[i] : 0;
        int s = v;
        #pragma unroll
        for (int off = 1; off < 64; off <<= 1) {
            int t = __shfl_up(s, off);
            if (lane >= off) s += t;
        }
        if (lane == 63) wsum[wv] = s;
        __syncthreads();
        if (wv == 0 && lane < 16) {
            int ws = wsum[lane];
            #pragma unroll
            for (int off = 1; off < 16; off <<= 1) {
                int t = __shfl_up(ws, off);
                if (lane >= off) ws += t;
            }
            wsum[lane] = ws;
        }
        __syncthreads();
        int carry = carry_sh;
        int woff = wv ? wsum[wv - 1] : 0;
        if (i < N_NODES) {
            int rp = carry + woff + s - v;
            row_ptr[i] = rp; cursor[i] = rp;
        }
        __syncthreads();
        if (threadIdx.x == 0) carry_sh = carry + wsum[15];
        __syncthreads();
    }
    if (threadIdx.x == 0) row_ptr[N_NODES] = carry_sh;
}

__global__ void fill_k(const int* __restrict__ ei, int* __restrict__ cursor,
                       int* __restrict__ col) {
    int e = blockIdx.x * blockDim.x + threadIdx.x;
    if (e >= E_TOT) return;
    int s, d;
    if (e < N_EDGES) { s = ei[e]; d = ei[N_EDGES + e]; }
    else { s = e - N_EDGES; d = s; }
    int slot = atomicAdd(&cursor[d], 1);
    col[slot] = s;
}

// ---------------- GEMM + fused scores; emits fp16 h only ----------------
template<int K, int NOUT>
__global__ __launch_bounds__(256) void gemm_k(const float* __restrict__ x,
                                              const float* __restrict__ W,
                                              const float* __restrict__ asrc,
                                              const float* __restrict__ adst,
                                              _Float16* __restrict__ outh,
                                              float* __restrict__ ssrc,
                                              float* __restrict__ sdst) {
    constexpr int VC = NOUT / 64;  // cols per lane (2 or 4)
    __shared__ float xs[32 * K];
    int row0 = blockIdx.x * 32;
    for (int idx = threadIdx.x; idx < 32 * K / 4; idx += 256) {
        int r = (idx * 4) / K, c = (idx * 4) % K;
        float4 v = make_float4(0.f, 0.f, 0.f, 0.f);
        if (row0 + r < N_NODES) v = *(const float4*)(x + (size_t)(row0 + r) * K + c);
        *(float4*)(xs + r * K + c) = v;
    }
    __syncthreads();
    int wave = threadIdx.x >> 6, lane = threadIdx.x & 63;
    int r0 = wave * 8;
    float acc[8][VC];
    #pragma unroll
    for (int r = 0; r < 8; ++r)
        #pragma unroll
        for (int c = 0; c < VC; ++c) acc[r][c] = 0.f;
    int colb = lane * VC;
    for (int k = 0; k < K; k += 4) {
        float4 xr[8];
        #pragma unroll
        for (int r = 0; r < 8; ++r) xr[r] = *(const float4*)(xs + (r0 + r) * K + k);
        #pragma unroll
        for (int kk = 0; kk < 4; ++kk) {
            float wv[VC];
            if constexpr (VC == 4) {
                float4 t = *(const float4*)(W + (size_t)(k + kk) * NOUT + colb);
                wv[0] = t.x; wv[1] = t.y; wv[2] = t.z; wv[3] = t.w;
            } else {
                float2 t = *(const float2*)(W + (size_t)(k + kk) * NOUT + colb);
                wv[0] = t.x; wv[1] = t.y;
            }
            #pragma unroll
            for (int r = 0; r < 8; ++r) {
                float xv = (kk == 0) ? xr[r].x : (kk == 1) ? xr[r].y
                         : (kk == 2) ? xr[r].z : xr[r].w;
                #pragma unroll
                for (int c = 0; c < VC; ++c) acc[r][c] += xv * wv[c];
            }
        }
    }
    float avs[VC], avd[VC];
    #pragma unroll
    for (int c = 0; c < VC; ++c) { avs[c] = asrc[colb + c]; avd[c] = adst[colb + c]; }
    int hd = lane >> 4, lg = lane & 15;
    #pragma unroll
    for (int r = 0; r < 8; ++r) {
        int row = row0 + r0 + r;
        if (row < N_NODES) {
            if constexpr (VC == 4) {
                h4v hh;
                #pragma unroll
                for (int c = 0; c < 4; ++c) hh[c] = (_Float16)acc[r][c];
                *(h4v*)(outh + (size_t)row * NOUT + colb) = hh;
            } else {
                h2v hh;
                #pragma unroll
                for (int c = 0; c < 2; ++c) hh[c] = (_Float16)acc[r][c];
                *(h2v*)(outh + (size_t)row * NOUT + colb) = hh;
            }
            float ps = 0.f, pd = 0.f;
            #pragma unroll
            for (int c = 0; c < VC; ++c) { ps += acc[r][c] * avs[c]; pd += acc[r][c] * avd[c]; }
            #pragma unroll
            for (int off = 1; off < 16; off <<= 1) {
                ps += __shfl_xor(ps, off);
                pd += __shfl_xor(pd, off);
            }
            if (lg == 0) {
                ssrc[row * NH + hd] = ps;
                sdst[row * NH + hd] = pd;
            }
        }
    }
}

// ---------------- normalized softmax weights -> per-head PLANES ----------------
// alpha[hd*E_TOT + e]; one wave per node, 16-lane group per head.
__global__ __launch_bounds__(256) void alpha_k(const float* __restrict__ ssrc,
                                               const float* __restrict__ sdst,
                                               const int* __restrict__ row_ptr,
                                               const int* __restrict__ col,
                                               float* __restrict__ alpha) {
    int wv = threadIdx.x >> 6, lane = threadIdx.x & 63;
    int v = blockIdx.x * 4 + wv;
    if (v >= N_NODES) return;
    int hd = lane >> 4, lg = lane & 15;
    int beg = row_ptr[v], cnt = row_ptr[v + 1] - beg;
    float sdv = sdst[v * NH + hd];
    float* pl = alpha + (size_t)hd * E_TOT + beg;

    if (cnt <= 128) {
        float er[8];
        float m = -FLT_MAX;
        #pragma unroll
        for (int i = 0; i < 8; ++i) {
            int j = lg + i * 16;
            if (j < cnt) {
                int u = col[beg + j];
                float e = ssrc[u * NH + hd] + sdv;
                e = (e > 0.f) ? e : 0.2f * e;
                er[i] = e;
                m = fmaxf(m, e);
            }
        }
        #pragma unroll
        for (int off = 1; off < 16; off <<= 1) m = fmaxf(m, __shfl_xor(m, off));
        float den = 0.f;
        #pragma unroll
        for (int i = 0; i < 8; ++i) {
            int j = lg + i * 16;
            if (j < cnt) { float w = __expf(er[i] - m); er[i] = w; den += w; }
        }
        #pragma unroll
        for (int off = 1; off < 16; off <<= 1) den += __shfl_xor(den, off);
        float inv = 1.f / (den + 1e-16f);
        #pragma unroll
        for (int i = 0; i < 8; ++i) {
            int j = lg + i * 16;
            if (j < cnt) pl[j] = er[i] * inv;
        }
    } else {
        float m = -FLT_MAX;
        for (int j = lg; j < cnt; j += 16) {
            int u = col[beg + j];
            float e = ssrc[u * NH + hd] + sdv;
            e = (e > 0.f) ? e : 0.2f * e;
            m = fmaxf(m, e);
        }
        #pragma unroll
        for (int off = 1; off < 16; off <<= 1) m = fmaxf(m, __shfl_xor(m, off));
        float den = 0.f;
        for (int j = lg; j < cnt; j += 16) {
            int u = col[beg + j];
            float e = ssrc[u * NH + hd] + sdv;
            e = (e > 0.f) ? e : 0.2f * e;
            den += __expf(e - m);
        }
        #pragma unroll
        for (int off = 1; off < 16; off <<= 1) den += __shfl_xor(den, off);
        float inv = 1.f / (den + 1e-16f);
        for (int j = lg; j < cnt; j += 16) {
            int u = col[beg + j];
            float e = ssrc[u * NH + hd] + sdv;
            e = (e > 0.f) ? e : 0.2f * e;
            pl[j] = __expf(e - m) * inv;
        }
    }
}

// ---------------- XCD-sharded aggregation: fp16 gathers, L2-resident slice ----------------
// slice s = blockIdx % 8 -> XCD s. SLICE feats/block; per-XCD h-slice working set:
// 50000*SLICE*2 B = 3.2 MB (Fo=64) / 1.6 MB (Fo=32) -> fits 4 MiB L2.
// LPN lanes/node x 8 halfs (16B) each; col/alpha streamed via nontemporal loads.
template<int HFo, int SLICE, int LPN>
__global__ __launch_bounds__(256) void agg2_k(const _Float16* __restrict__ hh,
                                              const float* __restrict__ alpha,
                                              const int* __restrict__ row_ptr,
                                              const int* __restrict__ col,
                                              const float* __restrict__ bias,
                                              float* __restrict__ out) {
    constexpr int Fo  = HFo / NH;
    constexpr int NPW = 64 / LPN;   // nodes per wave
    constexpr int NPB = 4 * NPW;    // nodes per block
    int s = blockIdx.x & 7;
    int g = blockIdx.x >> 3;
    int wv = threadIdx.x >> 6, lane = threadIdx.x & 63;
    int sub = lane / LPN, lq = lane % LPN;
    int v = g * NPB + wv * NPW + sub;
    if (v >= N_NODES) return;
    int f0 = s * SLICE + lq * 8;
    int hd = (s * SLICE) / Fo;      // uniform per block
    int beg = row_ptr[v], cnt = row_ptr[v + 1] - beg;
    const int*   cp = col + beg;
    const float* ap = alpha + (size_t)hd * E_TOT + beg;

    float acc[8] = {};
    int j = 0;
    for (; j + 8 <= cnt; j += 8) {
        int u[8]; float w[8]; h8v hv[8];
        #pragma unroll
        for (int i = 0; i < 8; ++i) u[i] = __builtin_nontemporal_load(cp + j + i);
        #pragma unroll
        for (int i = 0; i < 8; ++i) w[i] = __builtin_nontemporal_load(ap + j + i);
        #pragma unroll
        for (int i = 0; i < 8; ++i) hv[i] = *(const h8v*)(hh + (size_t)u[i] * HFo + f0);
        #pragma unroll
        for (int i = 0; i < 8; ++i)
            #pragma unroll
            for (int c = 0; c < 8; ++c) acc[c] += w[i] * (float)hv[i][c];
    }
    for (; j < cnt; ++j) {
        int u = __builtin_nontemporal_load(cp + j);
        float w = __builtin_nontemporal_load(ap + j);
        h8v hv = *(const h8v*)(hh + (size_t)u * HFo + f0);
        #pragma unroll
        for (int c = 0; c < 8; ++c) acc[c] += w * (float)hv[c];
    }
    f4 b0 = *(const f4*)(bias + f0);
    f4 b1 = *(const f4*)(bias + f0 + 4);
    f4 r0, r1;
    #pragma unroll
    for (int c = 0; c < 4; ++c) {
        r0[c] = fmaxf(acc[c] + b0[c], 0.f);
        r1[c] = fmaxf(acc[c + 4] + b1[c], 0.f);
    }
    __builtin_nontemporal_store(r0, (f4*)(out + (size_t)v * HFo + f0));
    __builtin_nontemporal_store(r1, (f4*)(out + (size_t)v * HFo + f0 + 4));
}

// ---------------- pooling (batch_index sorted -> run-length pre-agg) ----------------
__global__ void pool_k(const float* __restrict__ h, const int* __restrict__ batch,
                       float* __restrict__ gsum, float* __restrict__ gmax) {
    int f = threadIdx.x;  // 256
    int n0 = blockIdx.x * 32;
    int nend = min(n0 + 32, N_NODES);
    int cur = -1;
    float sa = 0.f, ma = 0.f;
    for (int n = n0; n < nend; ++n) {
        int g = batch[n];
        float val = h[(size_t)n * 256 + f];
        if (g != cur) {
            if (cur >= 0) {
                atomicAdd(&gsum[cur * 256 + f], sa);
                atomicMax((int*)&gmax[cur * 256 + f], __float_as_int(ma));
            }
            cur = g; sa = 0.f; ma = 0.f;
        }
        sa += val;
        ma = fmaxf(ma, val);
    }
    if (cur >= 0) {
        atomicAdd(&gsum[cur * 256 + f], sa);
        atomicMax((int*)&gmax[cur * 256 + f], __float_as_int(ma));
    }
}

// batch sorted -> per-graph count = boundary difference (binary search)
__global__ void gcnt_k(const int* __restrict__ batch, int* __restrict__ gcnt) {
    int g = threadIdx.x;  // 128 threads
    if (g >= NG) return;
    int lo = 0, hi = N_NODES;
    while (lo < hi) { int mid = (lo + hi) >> 1; if (batch[mid] < g) lo = mid + 1; else hi = mid; }
    int b0 = lo;
    lo = 0; hi = N_NODES;
    while (lo < hi) { int mid = (lo + hi) >> 1; if (batch[mid] < g + 1) lo = mid + 1; else hi = mid; }
    gcnt[g] = lo - b0;
}

__global__ void readout_k(const float* __restrict__ gsum, const float* __restrict__ gmax,
                          const int* __restrict__ gcnt, const float* __restrict__ Wout,
                          const float* __restrict__ bout, float* __restrict__ out) {
    int g = blockIdx.x, lane = threadIdx.x;
    float inv = 1.f / fmaxf((float)gcnt[g], 1.f);
    float acc[10];
    #pragma unroll
    for (int j = 0; j < 10; ++j) acc[j] = 0.f;
    for (int f = lane; f < 512; f += 64) {
        float p = (f < 256) ? gsum[g * 256 + f] * inv : gmax[g * 256 + (f - 256)];
        #pragma unroll
        for (int j = 0; j < 10; ++j) acc[j] += p * Wout[f * 10 + j];
    }
    #pragma unroll
    for (int j = 0; j < 10; ++j) {
        float a = acc[j];
        #pragma unroll
        for (int off = 32; off; off >>= 1) a += __shfl_xor(a, off);
        if (lane == 0) out[g * 10 + j] = a + bout[j];
    }
}

extern "C" void kernel_launch(void* const* d_in, const int* in_sizes, int n_in,
                              void* d_out, int out_size, void* d_ws, size_t ws_size,
                              hipStream_t stream) {
    const float* x    = (const float*)d_in[0];
    const int*   ei   = (const int*)d_in[1];
    const int*   batch= (const int*)d_in[2];
    const float* W0   = (const float*)d_in[3];
    const float* as0  = (const float*)d_in[4];
    const float* ad0  = (const float*)d_in[5];
    const float* b0   = (const float*)d_in[6];
    const float* W1   = (const float*)d_in[7];
    const float* as1  = (const float*)d_in[8];
    const float* ad1  = (const float*)d_in[9];
    const float* b1   = (const float*)d_in[10];
    const float* W2   = (const float*)d_in[11];
    const float* as2  = (const float*)d_in[12];
    const float* ad2  = (const float*)d_in[13];
    const float* b2   = (const float*)d_in[14];
    const float* Wout = (const float*)d_in[15];
    const float* bout = (const float*)d_in[16];
    float* out = (float*)d_out;

    char* ws = (char*)d_ws;
    size_t o = 0;
    auto take = [&](size_t bytes) { size_t r = o; o += (bytes + 255) & ~(size_t)255; return r; };
    size_t cnt_o  = take((size_t)N_NODES * 4);
    size_t gsum_o = take((size_t)NG * 256 * 4);
    size_t gmax_o = take((size_t)NG * 256 * 4);
    size_t gcnt_o = take((size_t)NG * 4);
    size_t zero_bytes = o;
    size_t rp_o   = take((size_t)(N_NODES + 1) * 4);
    size_t cur_o  = take((size_t)N_NODES * 4);
    size_t col_o  = take((size_t)E_TOT * 4);
    size_t ssrc_o = take((size_t)N_NODES * NH * 4);
    size_t sdst_o = take((size_t)N_NODES * NH * 4);
    size_t alp_o  = take((size_t)NH * E_TOT * 4);      // per-head planes
    size_t hh_o   = take((size_t)N_NODES * 256 * 2);   // fp16 h
    size_t bufX_o = take((size_t)N_NODES * 256 * 4);   // fp32 ping buffer

    int*      cnt    = (int*)(ws + cnt_o);
    float*    gsum   = (float*)(ws + gsum_o);
    float*    gmax   = (float*)(ws + gmax_o);
    int*      gcnt   = (int*)(ws + gcnt_o);
    int*      row_ptr= (int*)(ws + rp_o);
    int*      cursor = (int*)(ws + cur_o);
    int*      col    = (int*)(ws + col_o);
    float*    ssrc   = (float*)(ws + ssrc_o);
    float*    sdst   = (float*)(ws + sdst_o);
    float*    alpha  = (float*)(ws + alp_o);
    _Float16* hH     = (_Float16*)(ws + hh_o);
    float*    bufX   = (float*)(ws + bufX_o);

    (void)hipMemsetAsync(ws, 0, zero_bytes, stream);

    count_dst_k<<<(E_TOT + 255) / 256, 256, 0, stream>>>(ei, cnt);
    scan_k<<<1, 1024, 0, stream>>>(cnt, row_ptr, cursor);
    fill_k<<<(E_TOT + 255) / 256, 256, 0, stream>>>(ei, cursor, col);

    int gemm_grid  = (N_NODES + 31) / 32;
    int alpha_grid = (N_NODES + 3) / 4;
    // HFo=128: SLICE=16, LPN=2 -> NPB=128;  HFo=256: SLICE=32, LPN=4 -> NPB=64
    int agg128_grid = 8 * ((N_NODES + 127) / 128);
    int agg256_grid = 8 * ((N_NODES + 63) / 64);

    // layer 0: 128 -> H4*Fo32 (128)
    gemm_k<128, 128><<<gemm_grid, 256, 0, stream>>>(x, W0, as0, ad0, hH, ssrc, sdst);
    alpha_k<<<alpha_grid, 256, 0, stream>>>(ssrc, sdst, row_ptr, col, alpha);
    agg2_k<128, 16, 2><<<agg128_grid, 256, 0, stream>>>(hH, alpha, row_ptr, col, b0, bufX);

    // layer 1: 128 -> H4*Fo64 (256)
    gemm_k<128, 256><<<gemm_grid, 256, 0, stream>>>(bufX, W1, as1, ad1, hH, ssrc, sdst);
    alpha_k<<<alpha_grid, 256, 0, stream>>>(ssrc, sdst, row_ptr, col, alpha);
    agg2_k<256, 32, 4><<<agg256_grid, 256, 0, stream>>>(hH, alpha, row_ptr, col, b1, bufX);

    // layer 2: 256 -> H4*Fo64 (256)
    gemm_k<256, 256><<<gemm_grid, 256, 0, stream>>>(bufX, W2, as2, ad2, hH, ssrc, sdst);
    alpha_k<<<alpha_grid, 256, 0, stream>>>(ssrc, sdst, row_ptr, col, alpha);
    agg2_k<256, 32, 4><<<agg256_grid, 256, 0, stream>>>(hH, alpha, row_ptr, col, b2, bufX);

    // pooling + readout
    pool_k<<<(N_NODES + 31) / 32, 256, 0, stream>>>(bufX, batch, gsum, gmax);
    gcnt_k<<<1, 128, 0, stream>>>(batch, gcnt);
    readout_k<<<NG, 64, 0, stream>>>(gsum, gmax, gcnt, Wout, bout, out);
}

// Round 9
// 845.662 us; speedup vs baseline: 1.0849x; 1.0849x over previous
//
#include <hip/hip_runtime.h>
#include <cfloat>

#define N_NODES 50000
#define N_EDGES 800000
#define E_TOT   850000
#define NG      128
#define NH      4

typedef float f4 __attribute__((ext_vector_type(4)));
typedef _Float16 h2v __attribute__((ext_vector_type(2)));
typedef _Float16 h4v __attribute__((ext_vector_type(4)));
typedef _Float16 h8v __attribute__((ext_vector_type(8)));

// ---------------- CSR build (by destination) ----------------
__global__ void count_dst_k(const int* __restrict__ ei, int* __restrict__ cnt) {
    int e = blockIdx.x * blockDim.x + threadIdx.x;
    if (e >= E_TOT) return;
    int d = (e < N_EDGES) ? ei[N_EDGES + e] : (e - N_EDGES);
    atomicAdd(&cnt[d], 1);
}

__global__ void scan_k(const int* __restrict__ cnt, int* __restrict__ row_ptr,
                       int* __restrict__ cursor) {
    __shared__ int wsum[16];
    __shared__ int carry_sh;
    int lane = threadIdx.x & 63, wv = threadIdx.x >> 6;
    if (threadIdx.x == 0) carry_sh = 0;
    __syncthreads();
    for (int base = 0; base < N_NODES; base += 1024) {
        int i = base + threadIdx.x;
        int v = (i < N_NODES) ? cnt[i] : 0;
        int s = v;
        #pragma unroll
        for (int off = 1; off < 64; off <<= 1) {
            int t = __shfl_up(s, off);
            if (lane >= off) s += t;
        }
        if (lane == 63) wsum[wv] = s;
        __syncthreads();
        if (wv == 0 && lane < 16) {
            int ws = wsum[lane];
            #pragma unroll
            for (int off = 1; off < 16; off <<= 1) {
                int t = __shfl_up(ws, off);
                if (lane >= off) ws += t;
            }
            wsum[lane] = ws;
        }
        __syncthreads();
        int carry = carry_sh;
        int woff = wv ? wsum[wv - 1] : 0;
        if (i < N_NODES) {
            int rp = carry + woff + s - v;
            row_ptr[i] = rp; cursor[i] = rp;
        }
        __syncthreads();
        if (threadIdx.x == 0) carry_sh = carry + wsum[15];
        __syncthreads();
    }
    if (threadIdx.x == 0) row_ptr[N_NODES] = carry_sh;
}

__global__ void fill_k(const int* __restrict__ ei, int* __restrict__ cursor,
                       int* __restrict__ col) {
    int e = blockIdx.x * blockDim.x + threadIdx.x;
    if (e >= E_TOT) return;
    int s, d;
    if (e < N_EDGES) { s = ei[e]; d = ei[N_EDGES + e]; }
    else { s = e - N_EDGES; d = s; }
    int slot = atomicAdd(&cursor[d], 1);
    col[slot] = s;
}

// ---------------- GEMM + fused scores; emits fp16 h in SLICE-MAJOR layout ----------------
// hh[s][node][SLICE]: slice s (SLICE=NOUT/8 feats) contiguous per 8-way XCD shard.
template<int K, int NOUT>
__global__ __launch_bounds__(256) void gemm_k(const float* __restrict__ x,
                                              const float* __restrict__ W,
                                              const float* __restrict__ asrc,
                                              const float* __restrict__ adst,
                                              _Float16* __restrict__ outh,
                                              float* __restrict__ ssrc,
                                              float* __restrict__ sdst) {
    constexpr int VC = NOUT / 64;      // cols per lane (2 or 4)
    constexpr int SLICE = NOUT / 8;    // feats per slice
    __shared__ float xs[32 * K];
    int row0 = blockIdx.x * 32;
    for (int idx = threadIdx.x; idx < 32 * K / 4; idx += 256) {
        int r = (idx * 4) / K, c = (idx * 4) % K;
        float4 v = make_float4(0.f, 0.f, 0.f, 0.f);
        if (row0 + r < N_NODES) v = *(const float4*)(x + (size_t)(row0 + r) * K + c);
        *(float4*)(xs + r * K + c) = v;
    }
    __syncthreads();
    int wave = threadIdx.x >> 6, lane = threadIdx.x & 63;
    int r0 = wave * 8;
    float acc[8][VC];
    #pragma unroll
    for (int r = 0; r < 8; ++r)
        #pragma unroll
        for (int c = 0; c < VC; ++c) acc[r][c] = 0.f;
    int colb = lane * VC;
    for (int k = 0; k < K; k += 4) {
        float4 xr[8];
        #pragma unroll
        for (int r = 0; r < 8; ++r) xr[r] = *(const float4*)(xs + (r0 + r) * K + k);
        #pragma unroll
        for (int kk = 0; kk < 4; ++kk) {
            float wv[VC];
            if constexpr (VC == 4) {
                float4 t = *(const float4*)(W + (size_t)(k + kk) * NOUT + colb);
                wv[0] = t.x; wv[1] = t.y; wv[2] = t.z; wv[3] = t.w;
            } else {
                float2 t = *(const float2*)(W + (size_t)(k + kk) * NOUT + colb);
                wv[0] = t.x; wv[1] = t.y;
            }
            #pragma unroll
            for (int r = 0; r < 8; ++r) {
                float xv = (kk == 0) ? xr[r].x : (kk == 1) ? xr[r].y
                         : (kk == 2) ? xr[r].z : xr[r].w;
                #pragma unroll
                for (int c = 0; c < VC; ++c) acc[r][c] += xv * wv[c];
            }
        }
    }
    float avs[VC], avd[VC];
    #pragma unroll
    for (int c = 0; c < VC; ++c) { avs[c] = asrc[colb + c]; avd[c] = adst[colb + c]; }
    int hd = lane >> 4, lg = lane & 15;
    int sl = colb / SLICE, so = colb % SLICE;   // slice id / offset within slice
    _Float16* wp = outh + (size_t)sl * N_NODES * SLICE + so;
    #pragma unroll
    for (int r = 0; r < 8; ++r) {
        int row = row0 + r0 + r;
        if (row < N_NODES) {
            if constexpr (VC == 4) {
                h4v hh;
                #pragma unroll
                for (int c = 0; c < 4; ++c) hh[c] = (_Float16)acc[r][c];
                *(h4v*)(wp + (size_t)row * SLICE) = hh;
            } else {
                h2v hh;
                #pragma unroll
                for (int c = 0; c < 2; ++c) hh[c] = (_Float16)acc[r][c];
                *(h2v*)(wp + (size_t)row * SLICE) = hh;
            }
            float ps = 0.f, pd = 0.f;
            #pragma unroll
            for (int c = 0; c < VC; ++c) { ps += acc[r][c] * avs[c]; pd += acc[r][c] * avd[c]; }
            #pragma unroll
            for (int off = 1; off < 16; off <<= 1) {
                ps += __shfl_xor(ps, off);
                pd += __shfl_xor(pd, off);
            }
            if (lg == 0) {
                ssrc[row * NH + hd] = ps;
                sdst[row * NH + hd] = pd;
            }
        }
    }
}

// ---------------- normalized softmax weights -> per-head PLANES ----------------
// alpha[hd*E_TOT + e]; one wave per node, 16-lane group per head.
__global__ __launch_bounds__(256) void alpha_k(const float* __restrict__ ssrc,
                                               const float* __restrict__ sdst,
                                               const int* __restrict__ row_ptr,
                                               const int* __restrict__ col,
                                               float* __restrict__ alpha) {
    int wv = threadIdx.x >> 6, lane = threadIdx.x & 63;
    int v = blockIdx.x * 4 + wv;
    if (v >= N_NODES) return;
    int hd = lane >> 4, lg = lane & 15;
    int beg = row_ptr[v], cnt = row_ptr[v + 1] - beg;
    float sdv = sdst[v * NH + hd];
    float* pl = alpha + (size_t)hd * E_TOT + beg;

    if (cnt <= 128) {
        float er[8];
        float m = -FLT_MAX;
        #pragma unroll
        for (int i = 0; i < 8; ++i) {
            int j = lg + i * 16;
            if (j < cnt) {
                int u = col[beg + j];
                float e = ssrc[u * NH + hd] + sdv;
                e = (e > 0.f) ? e : 0.2f * e;
                er[i] = e;
                m = fmaxf(m, e);
            }
        }
        #pragma unroll
        for (int off = 1; off < 16; off <<= 1) m = fmaxf(m, __shfl_xor(m, off));
        float den = 0.f;
        #pragma unroll
        for (int i = 0; i < 8; ++i) {
            int j = lg + i * 16;
            if (j < cnt) { float w = __expf(er[i] - m); er[i] = w; den += w; }
        }
        #pragma unroll
        for (int off = 1; off < 16; off <<= 1) den += __shfl_xor(den, off);
        float inv = 1.f / (den + 1e-16f);
        #pragma unroll
        for (int i = 0; i < 8; ++i) {
            int j = lg + i * 16;
            if (j < cnt) pl[j] = er[i] * inv;
        }
    } else {
        float m = -FLT_MAX;
        for (int j = lg; j < cnt; j += 16) {
            int u = col[beg + j];
            float e = ssrc[u * NH + hd] + sdv;
            e = (e > 0.f) ? e : 0.2f * e;
            m = fmaxf(m, e);
        }
        #pragma unroll
        for (int off = 1; off < 16; off <<= 1) m = fmaxf(m, __shfl_xor(m, off));
        float den = 0.f;
        for (int j = lg; j < cnt; j += 16) {
            int u = col[beg + j];
            float e = ssrc[u * NH + hd] + sdv;
            e = (e > 0.f) ? e : 0.2f * e;
            den += __expf(e - m);
        }
        #pragma unroll
        for (int off = 1; off < 16; off <<= 1) den += __shfl_xor(den, off);
        float inv = 1.f / (den + 1e-16f);
        for (int j = lg; j < cnt; j += 16) {
            int u = col[beg + j];
            float e = ssrc[u * NH + hd] + sdv;
            e = (e > 0.f) ? e : 0.2f * e;
            pl[j] = __expf(e - m) * inv;
        }
    }
}

// ---------------- XCD-sharded aggregation: slice-major fp16, L2-resident ----------------
// slice s = blockIdx % 8 -> XCD s. hh slice region CONTIGUOUS:
// 50000*SLICE*2 B = 3.2 MB (SLICE=32) / 1.6 MB (SLICE=16) < 4 MiB L2.
template<int HFo, int SLICE, int LPN>
__global__ __launch_bounds__(256) void agg2_k(const _Float16* __restrict__ hh,
                                              const float* __restrict__ alpha,
                                              const int* __restrict__ row_ptr,
                                              const int* __restrict__ col,
                                              const float* __restrict__ bias,
                                              float* __restrict__ out) {
    constexpr int Fo  = HFo / NH;
    constexpr int NPW = 64 / LPN;   // nodes per wave
    constexpr int NPB = 4 * NPW;    // nodes per block
    int s = blockIdx.x & 7;
    int g = blockIdx.x >> 3;
    int wv = threadIdx.x >> 6, lane = threadIdx.x & 63;
    int sub = lane / LPN, lq = lane % LPN;
    int v = g * NPB + wv * NPW + sub;
    if (v >= N_NODES) return;
    int f0 = s * SLICE + lq * 8;    // global feature index (bias/out)
    int hd = (s * SLICE) / Fo;      // uniform per block
    int beg = row_ptr[v], cnt = row_ptr[v + 1] - beg;
    const int*      cp = col + beg;
    const float*    ap = alpha + (size_t)hd * E_TOT + beg;
    const _Float16* hp = hh + (size_t)s * N_NODES * SLICE + lq * 8;

    float acc[8] = {};
    int j = 0;
    for (; j + 8 <= cnt; j += 8) {
        int u[8]; float w[8]; h8v hv[8];
        #pragma unroll
        for (int i = 0; i < 8; ++i) u[i] = __builtin_nontemporal_load(cp + j + i);
        #pragma unroll
        for (int i = 0; i < 8; ++i) w[i] = __builtin_nontemporal_load(ap + j + i);
        #pragma unroll
        for (int i = 0; i < 8; ++i) hv[i] = *(const h8v*)(hp + (size_t)u[i] * SLICE);
        #pragma unroll
        for (int i = 0; i < 8; ++i)
            #pragma unroll
            for (int c = 0; c < 8; ++c) acc[c] += w[i] * (float)hv[i][c];
    }
    for (; j < cnt; ++j) {
        int u = __builtin_nontemporal_load(cp + j);
        float w = __builtin_nontemporal_load(ap + j);
        h8v hv = *(const h8v*)(hp + (size_t)u * SLICE);
        #pragma unroll
        for (int c = 0; c < 8; ++c) acc[c] += w * (float)hv[c];
    }
    f4 b0 = *(const f4*)(bias + f0);
    f4 b1 = *(const f4*)(bias + f0 + 4);
    f4 r0, r1;
    #pragma unroll
    for (int c = 0; c < 4; ++c) {
        r0[c] = fmaxf(acc[c] + b0[c], 0.f);
        r1[c] = fmaxf(acc[c + 4] + b1[c], 0.f);
    }
    __builtin_nontemporal_store(r0, (f4*)(out + (size_t)v * HFo + f0));
    __builtin_nontemporal_store(r1, (f4*)(out + (size_t)v * HFo + f0 + 4));
}

// ---------------- pooling (batch_index sorted -> run-length pre-agg) ----------------
__global__ void pool_k(const float* __restrict__ h, const int* __restrict__ batch,
                       float* __restrict__ gsum, float* __restrict__ gmax) {
    int f = threadIdx.x;  // 256
    int n0 = blockIdx.x * 32;
    int nend = min(n0 + 32, N_NODES);
    int cur = -1;
    float sa = 0.f, ma = 0.f;
    for (int n = n0; n < nend; ++n) {
        int g = batch[n];
        float val = h[(size_t)n * 256 + f];
        if (g != cur) {
            if (cur >= 0) {
                atomicAdd(&gsum[cur * 256 + f], sa);
                atomicMax((int*)&gmax[cur * 256 + f], __float_as_int(ma));
            }
            cur = g; sa = 0.f; ma = 0.f;
        }
        sa += val;
        ma = fmaxf(ma, val);
    }
    if (cur >= 0) {
        atomicAdd(&gsum[cur * 256 + f], sa);
        atomicMax((int*)&gmax[cur * 256 + f], __float_as_int(ma));
    }
}

// batch sorted -> per-graph count = boundary difference (binary search)
__global__ void gcnt_k(const int* __restrict__ batch, int* __restrict__ gcnt) {
    int g = threadIdx.x;  // 128 threads
    if (g >= NG) return;
    int lo = 0, hi = N_NODES;
    while (lo < hi) { int mid = (lo + hi) >> 1; if (batch[mid] < g) lo = mid + 1; else hi = mid; }
    int b0 = lo;
    lo = 0; hi = N_NODES;
    while (lo < hi) { int mid = (lo + hi) >> 1; if (batch[mid] < g + 1) lo = mid + 1; else hi = mid; }
    gcnt[g] = lo - b0;
}

__global__ void readout_k(const float* __restrict__ gsum, const float* __restrict__ gmax,
                          const int* __restrict__ gcnt, const float* __restrict__ Wout,
                          const float* __restrict__ bout, float* __restrict__ out) {
    int g = blockIdx.x, lane = threadIdx.x;
    float inv = 1.f / fmaxf((float)gcnt[g], 1.f);
    float acc[10];
    #pragma unroll
    for (int j = 0; j < 10; ++j) acc[j] = 0.f;
    for (int f = lane; f < 512; f += 64) {
        float p = (f < 256) ? gsum[g * 256 + f] * inv : gmax[g * 256 + (f - 256)];
        #pragma unroll
        for (int j = 0; j < 10; ++j) acc[j] += p * Wout[f * 10 + j];
    }
    #pragma unroll
    for (int j = 0; j < 10; ++j) {
        float a = acc[j];
        #pragma unroll
        for (int off = 32; off; off >>= 1) a += __shfl_xor(a, off);
        if (lane == 0) out[g * 10 + j] = a + bout[j];
    }
}

extern "C" void kernel_launch(void* const* d_in, const int* in_sizes, int n_in,
                              void* d_out, int out_size, void* d_ws, size_t ws_size,
                              hipStream_t stream) {
    const float* x    = (const float*)d_in[0];
    const int*   ei   = (const int*)d_in[1];
    const int*   batch= (const int*)d_in[2];
    const float* W0   = (const float*)d_in[3];
    const float* as0  = (const float*)d_in[4];
    const float* ad0  = (const float*)d_in[5];
    const float* b0   = (const float*)d_in[6];
    const float* W1   = (const float*)d_in[7];
    const float* as1  = (const float*)d_in[8];
    const float* ad1  = (const float*)d_in[9];
    const float* b1   = (const float*)d_in[10];
    const float* W2   = (const float*)d_in[11];
    const float* as2  = (const float*)d_in[12];
    const float* ad2  = (const float*)d_in[13];
    const float* b2   = (const float*)d_in[14];
    const float* Wout = (const float*)d_in[15];
    const float* bout = (const float*)d_in[16];
    float* out = (float*)d_out;

    char* ws = (char*)d_ws;
    size_t o = 0;
    auto take = [&](size_t bytes) { size_t r = o; o += (bytes + 255) & ~(size_t)255; return r; };
    size_t cnt_o  = take((size_t)N_NODES * 4);
    size_t gsum_o = take((size_t)NG * 256 * 4);
    size_t gmax_o = take((size_t)NG * 256 * 4);
    size_t gcnt_o = take((size_t)NG * 4);
    size_t zero_bytes = o;
    size_t rp_o   = take((size_t)(N_NODES + 1) * 4);
    size_t cur_o  = take((size_t)N_NODES * 4);
    size_t col_o  = take((size_t)E_TOT * 4);
    size_t ssrc_o = take((size_t)N_NODES * NH * 4);
    size_t sdst_o = take((size_t)N_NODES * NH * 4);
    size_t alp_o  = take((size_t)NH * E_TOT * 4);      // per-head planes
    size_t hh_o   = take((size_t)N_NODES * 256 * 2);   // fp16 h (slice-major)
    size_t bufX_o = take((size_t)N_NODES * 256 * 4);   // fp32 ping buffer

    int*      cnt    = (int*)(ws + cnt_o);
    float*    gsum   = (float*)(ws + gsum_o);
    float*    gmax   = (float*)(ws + gmax_o);
    int*      gcnt   = (int*)(ws + gcnt_o);
    int*      row_ptr= (int*)(ws + rp_o);
    int*      cursor = (int*)(ws + cur_o);
    int*      col    = (int*)(ws + col_o);
    float*    ssrc   = (float*)(ws + ssrc_o);
    float*    sdst   = (float*)(ws + sdst_o);
    float*    alpha  = (float*)(ws + alp_o);
    _Float16* hH     = (_Float16*)(ws + hh_o);
    float*    bufX   = (float*)(ws + bufX_o);

    (void)hipMemsetAsync(ws, 0, zero_bytes, stream);

    count_dst_k<<<(E_TOT + 255) / 256, 256, 0, stream>>>(ei, cnt);
    scan_k<<<1, 1024, 0, stream>>>(cnt, row_ptr, cursor);
    fill_k<<<(E_TOT + 255) / 256, 256, 0, stream>>>(ei, cursor, col);

    int gemm_grid  = (N_NODES + 31) / 32;
    int alpha_grid = (N_NODES + 3) / 4;
    // HFo=128: SLICE=16, LPN=2 -> NPB=128;  HFo=256: SLICE=32, LPN=4 -> NPB=64
    int agg128_grid = 8 * ((N_NODES + 127) / 128);
    int agg256_grid = 8 * ((N_NODES + 63) / 64);

    // layer 0: 128 -> H4*Fo32 (128)
    gemm_k<128, 128><<<gemm_grid, 256, 0, stream>>>(x, W0, as0, ad0, hH, ssrc, sdst);
    alpha_k<<<alpha_grid, 256, 0, stream>>>(ssrc, sdst, row_ptr, col, alpha);
    agg2_k<128, 16, 2><<<agg128_grid, 256, 0, stream>>>(hH, alpha, row_ptr, col, b0, bufX);

    // layer 1: 128 -> H4*Fo64 (256)
    gemm_k<128, 256><<<gemm_grid, 256, 0, stream>>>(bufX, W1, as1, ad1, hH, ssrc, sdst);
    alpha_k<<<alpha_grid, 256, 0, stream>>>(ssrc, sdst, row_ptr, col, alpha);
    agg2_k<256, 32, 4><<<agg256_grid, 256, 0, stream>>>(hH, alpha, row_ptr, col, b1, bufX);

    // layer 2: 256 -> H4*Fo64 (256)
    gemm_k<256, 256><<<gemm_grid, 256, 0, stream>>>(bufX, W2, as2, ad2, hH, ssrc, sdst);
    alpha_k<<<alpha_grid, 256, 0, stream>>>(ssrc, sdst, row_ptr, col, alpha);
    agg2_k<256, 32, 4><<<agg256_grid, 256, 0, stream>>>(hH, alpha, row_ptr, col, b2, bufX);

    // pooling + readout
    pool_k<<<(N_NODES + 31) / 32, 256, 0, stream>>>(bufX, batch, gsum, gmax);
    gcnt_k<<<1, 128, 0, stream>>>(batch, gcnt);
    readout_k<<<NG, 64, 0, stream>>>(gsum, gmax, gcnt, Wout, bout, out);
}

// Round 10
// 597.365 us; speedup vs baseline: 1.5359x; 1.4157x over previous
//
#include <hip/hip_runtime.h>
#include <cfloat>

#define N_NODES 50000
#define N_EDGES 800000
#define E_TOT   850000
#define NG      128
#define NH      4
#define CHUNK   782   // ceil(N_NODES/64) for the 64-block scan

typedef float f4 __attribute__((ext_vector_type(4)));
typedef _Float16 h2v __attribute__((ext_vector_type(2)));
typedef _Float16 h4v __attribute__((ext_vector_type(4)));
typedef _Float16 h8v __attribute__((ext_vector_type(8)));

// ---------------- CSR build (by destination) ----------------
__global__ void count_dst_k(const int* __restrict__ ei, int* __restrict__ cnt) {
    int e = blockIdx.x * blockDim.x + threadIdx.x;
    if (e >= E_TOT) return;
    int d = (e < N_EDGES) ? ei[N_EDGES + e] : (e - N_EDGES);
    atomicAdd(&cnt[d], 1);
}

// 3-phase scan: per-block sums -> scan sums -> per-block full scan
__global__ void scan_sums_k(const int* __restrict__ cnt, int* __restrict__ bsum) {
    int b = blockIdx.x;
    int start = b * CHUNK, end2 = min(start + CHUNK, N_NODES);
    int lane = threadIdx.x & 63, wv = threadIdx.x >> 6;
    int s = 0;
    for (int i = start + threadIdx.x; i < end2; i += 256) s += cnt[i];
    #pragma unroll
    for (int off = 32; off; off >>= 1) s += __shfl_xor(s, off);
    __shared__ int ws[4];
    if (lane == 0) ws[wv] = s;
    __syncthreads();
    if (threadIdx.x == 0) bsum[b] = ws[0] + ws[1] + ws[2] + ws[3];
}

__global__ void scan_off_k(int* __restrict__ bsum, int* __restrict__ row_ptr) {
    int lane = threadIdx.x;  // 64 threads
    int v = bsum[lane];
    int s = v;
    #pragma unroll
    for (int off = 1; off < 64; off <<= 1) {
        int t = __shfl_up(s, off);
        if (lane >= off) s += t;
    }
    bsum[lane] = s - v;  // exclusive
    if (lane == 63) row_ptr[N_NODES] = s;
}

__global__ void scan_write_k(const int* __restrict__ cnt, const int* __restrict__ bsum,
                             int* __restrict__ row_ptr, int* __restrict__ cursor) {
    int b = blockIdx.x;
    int start = b * CHUNK, end2 = min(start + CHUNK, N_NODES);
    __shared__ int wsum[4];
    __shared__ int carry_sh;
    int lane = threadIdx.x & 63, wv = threadIdx.x >> 6;
    if (threadIdx.x == 0) carry_sh = bsum[b];
    __syncthreads();
    for (int base = start; base < end2; base += 256) {
        int i = base + threadIdx.x;
        int v = (i < end2) ? cnt[i] : 0;
        int s = v;
        #pragma unroll
        for (int off = 1; off < 64; off <<= 1) {
            int t = __shfl_up(s, off);
            if (lane >= off) s += t;
        }
        if (lane == 63) wsum[wv] = s;
        __syncthreads();
        int woff = 0;
        #pragma unroll
        for (int k = 0; k < 4; ++k) if (k < wv) woff += wsum[k];
        int carry = carry_sh;
        if (i < end2) { int rp = carry + woff + s - v; row_ptr[i] = rp; cursor[i] = rp; }
        __syncthreads();
        if (threadIdx.x == 0) carry_sh = carry + wsum[0] + wsum[1] + wsum[2] + wsum[3];
        __syncthreads();
    }
}

__global__ void fill_k(const int* __restrict__ ei, int* __restrict__ cursor,
                       int* __restrict__ col) {
    int e = blockIdx.x * blockDim.x + threadIdx.x;
    if (e >= E_TOT) return;
    int s, d;
    if (e < N_EDGES) { s = ei[e]; d = ei[N_EDGES + e]; }
    else { s = e - N_EDGES; d = s; }
    int slot = atomicAdd(&cursor[d], 1);
    col[slot] = s;
}

// ---------------- GEMM + fused scores; emits fp16 h SLICE-MAJOR ----------------
// XT = float (layer 0) or _Float16 (layers 1,2). hh[s][node][SLICE].
template<int K, int NOUT, typename XT>
__global__ __launch_bounds__(256) void gemm_k(const XT* __restrict__ x,
                                              const float* __restrict__ W,
                                              const float* __restrict__ asrc,
                                              const float* __restrict__ adst,
                                              _Float16* __restrict__ outh,
                                              float* __restrict__ ssrc,
                                              float* __restrict__ sdst) {
    constexpr int VC = NOUT / 64;      // cols per lane (2 or 4)
    constexpr int SLICE = NOUT / 8;    // feats per XCD slice
    __shared__ float xs[32 * K];
    int row0 = blockIdx.x * 32;
    if constexpr (sizeof(XT) == 2) {
        for (int idx = threadIdx.x; idx < 32 * K / 8; idx += 256) {
            int r = (idx * 8) / K, c = (idx * 8) % K;
            h8v v = {};
            if (row0 + r < N_NODES) v = *(const h8v*)(x + (size_t)(row0 + r) * K + c);
            float4 a = make_float4((float)v[0], (float)v[1], (float)v[2], (float)v[3]);
            float4 b = make_float4((float)v[4], (float)v[5], (float)v[6], (float)v[7]);
            *(float4*)(xs + r * K + c) = a;
            *(float4*)(xs + r * K + c + 4) = b;
        }
    } else {
        for (int idx = threadIdx.x; idx < 32 * K / 4; idx += 256) {
            int r = (idx * 4) / K, c = (idx * 4) % K;
            float4 v = make_float4(0.f, 0.f, 0.f, 0.f);
            if (row0 + r < N_NODES) v = *(const float4*)((const float*)x + (size_t)(row0 + r) * K + c);
            *(float4*)(xs + r * K + c) = v;
        }
    }
    __syncthreads();
    int wave = threadIdx.x >> 6, lane = threadIdx.x & 63;
    int r0 = wave * 8;
    float acc[8][VC];
    #pragma unroll
    for (int r = 0; r < 8; ++r)
        #pragma unroll
        for (int c = 0; c < VC; ++c) acc[r][c] = 0.f;
    int colb = lane * VC;
    for (int k = 0; k < K; k += 4) {
        float4 xr[8];
        #pragma unroll
        for (int r = 0; r < 8; ++r) xr[r] = *(const float4*)(xs + (r0 + r) * K + k);
        #pragma unroll
        for (int kk = 0; kk < 4; ++kk) {
            float wv[VC];
            if constexpr (VC == 4) {
                float4 t = *(const float4*)(W + (size_t)(k + kk) * NOUT + colb);
                wv[0] = t.x; wv[1] = t.y; wv[2] = t.z; wv[3] = t.w;
            } else {
                float2 t = *(const float2*)(W + (size_t)(k + kk) * NOUT + colb);
                wv[0] = t.x; wv[1] = t.y;
            }
            #pragma unroll
            for (int r = 0; r < 8; ++r) {
                float xv = (kk == 0) ? xr[r].x : (kk == 1) ? xr[r].y
                         : (kk == 2) ? xr[r].z : xr[r].w;
                #pragma unroll
                for (int c = 0; c < VC; ++c) acc[r][c] += xv * wv[c];
            }
        }
    }
    float avs[VC], avd[VC];
    #pragma unroll
    for (int c = 0; c < VC; ++c) { avs[c] = asrc[colb + c]; avd[c] = adst[colb + c]; }
    int hd = lane >> 4, lg = lane & 15;
    int sl = colb / SLICE, so = colb % SLICE;
    _Float16* wp = outh + (size_t)sl * N_NODES * SLICE + so;
    #pragma unroll
    for (int r = 0; r < 8; ++r) {
        int row = row0 + r0 + r;
        if (row < N_NODES) {
            if constexpr (VC == 4) {
                h4v hh;
                #pragma unroll
                for (int c = 0; c < 4; ++c) hh[c] = (_Float16)acc[r][c];
                *(h4v*)(wp + (size_t)row * SLICE) = hh;
            } else {
                h2v hh;
                #pragma unroll
                for (int c = 0; c < 2; ++c) hh[c] = (_Float16)acc[r][c];
                *(h2v*)(wp + (size_t)row * SLICE) = hh;
            }
            float ps = 0.f, pd = 0.f;
            #pragma unroll
            for (int c = 0; c < VC; ++c) { ps += acc[r][c] * avs[c]; pd += acc[r][c] * avd[c]; }
            #pragma unroll
            for (int off = 1; off < 16; off <<= 1) {
                ps += __shfl_xor(ps, off);
                pd += __shfl_xor(pd, off);
            }
            if (lg == 0) {
                ssrc[row * NH + hd] = ps;
                sdst[row * NH + hd] = pd;
            }
        }
    }
}

// ---------------- normalized softmax weights -> per-head PLANES ----------------
__global__ __launch_bounds__(256) void alpha_k(const float* __restrict__ ssrc,
                                               const float* __restrict__ sdst,
                                               const int* __restrict__ row_ptr,
                                               const int* __restrict__ col,
                                               float* __restrict__ alpha) {
    int wv = threadIdx.x >> 6, lane = threadIdx.x & 63;
    int v = blockIdx.x * 4 + wv;
    if (v >= N_NODES) return;
    int hd = lane >> 4, lg = lane & 15;
    int beg = row_ptr[v], cnt = row_ptr[v + 1] - beg;
    float sdv = sdst[v * NH + hd];
    float* pl = alpha + (size_t)hd * E_TOT + beg;

    if (cnt <= 128) {
        float er[8];
        float m = -FLT_MAX;
        #pragma unroll
        for (int i = 0; i < 8; ++i) {
            int j = lg + i * 16;
            if (j < cnt) {
                int u = col[beg + j];
                float e = ssrc[u * NH + hd] + sdv;
                e = (e > 0.f) ? e : 0.2f * e;
                er[i] = e;
                m = fmaxf(m, e);
            }
        }
        #pragma unroll
        for (int off = 1; off < 16; off <<= 1) m = fmaxf(m, __shfl_xor(m, off));
        float den = 0.f;
        #pragma unroll
        for (int i = 0; i < 8; ++i) {
            int j = lg + i * 16;
            if (j < cnt) { float w = __expf(er[i] - m); er[i] = w; den += w; }
        }
        #pragma unroll
        for (int off = 1; off < 16; off <<= 1) den += __shfl_xor(den, off);
        float inv = 1.f / (den + 1e-16f);
        #pragma unroll
        for (int i = 0; i < 8; ++i) {
            int j = lg + i * 16;
            if (j < cnt) pl[j] = er[i] * inv;
        }
    } else {
        float m = -FLT_MAX;
        for (int j = lg; j < cnt; j += 16) {
            int u = col[beg + j];
            float e = ssrc[u * NH + hd] + sdv;
            e = (e > 0.f) ? e : 0.2f * e;
            m = fmaxf(m, e);
        }
        #pragma unroll
        for (int off = 1; off < 16; off <<= 1) m = fmaxf(m, __shfl_xor(m, off));
        float den = 0.f;
        for (int j = lg; j < cnt; j += 16) {
            int u = col[beg + j];
            float e = ssrc[u * NH + hd] + sdv;
            e = (e > 0.f) ? e : 0.2f * e;
            den += __expf(e - m);
        }
        #pragma unroll
        for (int off = 1; off < 16; off <<= 1) den += __shfl_xor(den, off);
        float inv = 1.f / (den + 1e-16f);
        for (int j = lg; j < cnt; j += 16) {
            int u = col[beg + j];
            float e = ssrc[u * NH + hd] + sdv;
            e = (e > 0.f) ? e : 0.2f * e;
            pl[j] = __expf(e - m) * inv;
        }
    }
}

// ---------------- XCD-sharded aggregation, wave-span LDS staging ----------------
// A wave's NPW consecutive nodes own ONE CONTIGUOUS span of col[]/alpha-plane.
// Stage the span into LDS coalesced (once, no redundancy); gather loop then has
// only independent h-loads. Output fp16 row-major (next gemm / pool input).
template<int HFo, int SLICE, int LPN>
__global__ __launch_bounds__(256) void agg3_k(const _Float16* __restrict__ hh,
                                              const float* __restrict__ alpha,
                                              const int* __restrict__ row_ptr,
                                              const int* __restrict__ col,
                                              const float* __restrict__ bias,
                                              _Float16* __restrict__ outH) {
    constexpr int Fo   = HFo / NH;
    constexpr int NPW  = 64 / LPN;    // nodes per wave
    constexpr int NPB  = 4 * NPW;     // nodes per block
    constexpr int CAPW = NPW * 32;    // span capacity (avg deg 17, max ~45)
    __shared__ int   colS[4][CAPW];
    __shared__ float awS[4][CAPW];
    int s = blockIdx.x & 7;
    int g = blockIdx.x >> 3;
    int wv = threadIdx.x >> 6, lane = threadIdx.x & 63;
    int sub = lane / LPN, lq = lane % LPN;
    int vFirst = g * NPB + wv * NPW;
    if (vFirst >= N_NODES) return;
    int vCount = min(NPW, N_NODES - vFirst);
    int hd = (s * SLICE) / Fo;        // uniform per block
    const float* ap = alpha + (size_t)hd * E_TOT;
    int begW = row_ptr[vFirst];
    int endW = row_ptr[vFirst + vCount];
    int len = endW - begW;
    bool active = sub < vCount;
    int v = vFirst + sub;
    int beg = 0, cnt = 0;
    if (active) { beg = row_ptr[v]; cnt = row_ptr[v + 1] - beg; }
    const _Float16* hp = hh + (size_t)s * N_NODES * SLICE + lq * 8;
    float acc[8] = {};

    if (len <= CAPW) {
        for (int t = lane; t < len; t += 64) {
            colS[wv][t] = col[begW + t];
            awS[wv][t]  = ap[begW + t];
        }
        __builtin_amdgcn_wave_barrier();
        int off = beg - begW;
        int j = 0;
        for (; j + 8 <= cnt; j += 8) {
            int u[8]; float w[8]; h8v hv[8];
            #pragma unroll
            for (int i = 0; i < 8; ++i) { u[i] = colS[wv][off + j + i]; w[i] = awS[wv][off + j + i]; }
            #pragma unroll
            for (int i = 0; i < 8; ++i) hv[i] = *(const h8v*)(hp + (size_t)u[i] * SLICE);
            #pragma unroll
            for (int i = 0; i < 8; ++i)
                #pragma unroll
                for (int c = 0; c < 8; ++c) acc[c] += w[i] * (float)hv[i][c];
        }
        for (; j < cnt; ++j) {
            int u = colS[wv][off + j];
            float w = awS[wv][off + j];
            h8v hv = *(const h8v*)(hp + (size_t)u * SLICE);
            #pragma unroll
            for (int c = 0; c < 8; ++c) acc[c] += w * (float)hv[c];
        }
    } else {
        // direct-global fallback (span overflow — practically never)
        const int*   cp = col + beg;
        const float* app = ap + beg;
        for (int j = 0; j < cnt; ++j) {
            int u = cp[j];
            float w = app[j];
            h8v hv = *(const h8v*)(hp + (size_t)u * SLICE);
            #pragma unroll
            for (int c = 0; c < 8; ++c) acc[c] += w * (float)hv[c];
        }
    }
    if (active) {
        int f0 = s * SLICE + lq * 8;
        h8v res;
        #pragma unroll
        for (int c = 0; c < 8; ++c) res[c] = (_Float16)fmaxf(acc[c] + bias[f0 + c], 0.f);
        *(h8v*)(outH + (size_t)v * HFo + f0) = res;
    }
}

// ---------------- pooling (fp16 input; batch sorted -> run-length pre-agg) ----------------
__global__ void pool_k(const _Float16* __restrict__ h, const int* __restrict__ batch,
                       float* __restrict__ gsum, float* __restrict__ gmax) {
    int f = threadIdx.x;  // 256
    int n0 = blockIdx.x * 32;
    int nend = min(n0 + 32, N_NODES);
    int cur = -1;
    float sa = 0.f, ma = 0.f;
    for (int n = n0; n < nend; ++n) {
        int g = batch[n];
        float val = (float)h[(size_t)n * 256 + f];
        if (g != cur) {
            if (cur >= 0) {
                atomicAdd(&gsum[cur * 256 + f], sa);
                atomicMax((int*)&gmax[cur * 256 + f], __float_as_int(ma));
            }
            cur = g; sa = 0.f; ma = 0.f;
        }
        sa += val;
        ma = fmaxf(ma, val);
    }
    if (cur >= 0) {
        atomicAdd(&gsum[cur * 256 + f], sa);
        atomicMax((int*)&gmax[cur * 256 + f], __float_as_int(ma));
    }
}

__global__ void gcnt_k(const int* __restrict__ batch, int* __restrict__ gcnt) {
    int g = threadIdx.x;  // 128 threads
    if (g >= NG) return;
    int lo = 0, hi = N_NODES;
    while (lo < hi) { int mid = (lo + hi) >> 1; if (batch[mid] < g) lo = mid + 1; else hi = mid; }
    int b0 = lo;
    lo = 0; hi = N_NODES;
    while (lo < hi) { int mid = (lo + hi) >> 1; if (batch[mid] < g + 1) lo = mid + 1; else hi = mid; }
    gcnt[g] = lo - b0;
}

__global__ void readout_k(const float* __restrict__ gsum, const float* __restrict__ gmax,
                          const int* __restrict__ gcnt, const float* __restrict__ Wout,
                          const float* __restrict__ bout, float* __restrict__ out) {
    int g = blockIdx.x, lane = threadIdx.x;
    float inv = 1.f / fmaxf((float)gcnt[g], 1.f);
    float acc[10];
    #pragma unroll
    for (int j = 0; j < 10; ++j) acc[j] = 0.f;
    for (int f = lane; f < 512; f += 64) {
        float p = (f < 256) ? gsum[g * 256 + f] * inv : gmax[g * 256 + (f - 256)];
        #pragma unroll
        for (int j = 0; j < 10; ++j) acc[j] += p * Wout[f * 10 + j];
    }
    #pragma unroll
    for (int j = 0; j < 10; ++j) {
        float a = acc[j];
        #pragma unroll
        for (int off = 32; off; off >>= 1) a += __shfl_xor(a, off);
        if (lane == 0) out[g * 10 + j] = a + bout[j];
    }
}

extern "C" void kernel_launch(void* const* d_in, const int* in_sizes, int n_in,
                              void* d_out, int out_size, void* d_ws, size_t ws_size,
                              hipStream_t stream) {
    const float* x    = (const float*)d_in[0];
    const int*   ei   = (const int*)d_in[1];
    const int*   batch= (const int*)d_in[2];
    const float* W0   = (const float*)d_in[3];
    const float* as0  = (const float*)d_in[4];
    const float* ad0  = (const float*)d_in[5];
    const float* b0   = (const float*)d_in[6];
    const float* W1   = (const float*)d_in[7];
    const float* as1  = (const float*)d_in[8];
    const float* ad1  = (const float*)d_in[9];
    const float* b1   = (const float*)d_in[10];
    const float* W2   = (const float*)d_in[11];
    const float* as2  = (const float*)d_in[12];
    const float* ad2  = (const float*)d_in[13];
    const float* b2   = (const float*)d_in[14];
    const float* Wout = (const float*)d_in[15];
    const float* bout = (const float*)d_in[16];
    float* out = (float*)d_out;

    char* ws = (char*)d_ws;
    size_t o = 0;
    auto take = [&](size_t bytes) { size_t r = o; o += (bytes + 255) & ~(size_t)255; return r; };
    size_t cnt_o  = take((size_t)N_NODES * 4);
    size_t gsum_o = take((size_t)NG * 256 * 4);
    size_t gmax_o = take((size_t)NG * 256 * 4);
    size_t gcnt_o = take((size_t)NG * 4);
    size_t zero_bytes = o;
    size_t rp_o   = take((size_t)(N_NODES + 1) * 4);
    size_t cur_o  = take((size_t)N_NODES * 4);
    size_t bsum_o = take((size_t)64 * 4);
    size_t col_o  = take((size_t)E_TOT * 4);
    size_t ssrc_o = take((size_t)N_NODES * NH * 4);
    size_t sdst_o = take((size_t)N_NODES * NH * 4);
    size_t alp_o  = take((size_t)NH * E_TOT * 4);      // per-head planes
    size_t hh_o   = take((size_t)N_NODES * 256 * 2);   // fp16 h slice-major (gather)
    size_t bufH_o = take((size_t)N_NODES * 256 * 2);   // fp16 h row-major (gemm/pool in)

    int*      cnt    = (int*)(ws + cnt_o);
    float*    gsum   = (float*)(ws + gsum_o);
    float*    gmax   = (float*)(ws + gmax_o);
    int*      gcnt   = (int*)(ws + gcnt_o);
    int*      row_ptr= (int*)(ws + rp_o);
    int*      cursor = (int*)(ws + cur_o);
    int*      bsum   = (int*)(ws + bsum_o);
    int*      col    = (int*)(ws + col_o);
    float*    ssrc   = (float*)(ws + ssrc_o);
    float*    sdst   = (float*)(ws + sdst_o);
    float*    alpha  = (float*)(ws + alp_o);
    _Float16* hH     = (_Float16*)(ws + hh_o);
    _Float16* bufH   = (_Float16*)(ws + bufH_o);

    (void)hipMemsetAsync(ws, 0, zero_bytes, stream);

    count_dst_k<<<(E_TOT + 255) / 256, 256, 0, stream>>>(ei, cnt);
    scan_sums_k<<<64, 256, 0, stream>>>(cnt, bsum);
    scan_off_k<<<1, 64, 0, stream>>>(bsum, row_ptr);
    scan_write_k<<<64, 256, 0, stream>>>(cnt, bsum, row_ptr, cursor);
    fill_k<<<(E_TOT + 255) / 256, 256, 0, stream>>>(ei, cursor, col);

    int gemm_grid  = (N_NODES + 31) / 32;
    int alpha_grid = (N_NODES + 3) / 4;
    // agg3: HFo=128: LPN=2, NPB=128; HFo=256: LPN=4, NPB=64
    int agg128_grid = 8 * ((N_NODES + 127) / 128);
    int agg256_grid = 8 * ((N_NODES + 63) / 64);

    // layer 0: 128 -> H4*Fo32 (128)
    gemm_k<128, 128, float><<<gemm_grid, 256, 0, stream>>>(x, W0, as0, ad0, hH, ssrc, sdst);
    alpha_k<<<alpha_grid, 256, 0, stream>>>(ssrc, sdst, row_ptr, col, alpha);
    agg3_k<128, 16, 2><<<agg128_grid, 256, 0, stream>>>(hH, alpha, row_ptr, col, b0, bufH);

    // layer 1: 128 -> H4*Fo64 (256)
    gemm_k<128, 256, _Float16><<<gemm_grid, 256, 0, stream>>>(bufH, W1, as1, ad1, hH, ssrc, sdst);
    alpha_k<<<alpha_grid, 256, 0, stream>>>(ssrc, sdst, row_ptr, col, alpha);
    agg3_k<256, 32, 4><<<agg256_grid, 256, 0, stream>>>(hH, alpha, row_ptr, col, b1, bufH);

    // layer 2: 256 -> H4*Fo64 (256)
    gemm_k<256, 256, _Float16><<<gemm_grid, 256, 0, stream>>>(bufH, W2, as2, ad2, hH, ssrc, sdst);
    alpha_k<<<alpha_grid, 256, 0, stream>>>(ssrc, sdst, row_ptr, col, alpha);
    agg3_k<256, 32, 4><<<agg256_grid, 256, 0, stream>>>(hH, alpha, row_ptr, col, b2, bufH);

    // pooling + readout
    pool_k<<<(N_NODES + 31) / 32, 256, 0, stream>>>(bufH, batch, gsum, gmax);
    gcnt_k<<<1, 128, 0, stream>>>(batch, gcnt);
    readout_k<<<NG, 64, 0, stream>>>(gsum, gmax, gcnt, Wout, bout, out);
}

// Round 11
// 533.153 us; speedup vs baseline: 1.7209x; 1.1204x over previous
//
#include <hip/hip_runtime.h>
#include <cfloat>

#define N_NODES 50000
#define N_EDGES 800000
#define E_TOT   850000
#define NG      128
#define NH      4
#define CHUNK   782   // ceil(N_NODES/64) for the 64-block scan

typedef float f4 __attribute__((ext_vector_type(4)));
typedef float v4f __attribute__((ext_vector_type(4)));
typedef _Float16 h2v __attribute__((ext_vector_type(2)));
typedef _Float16 h8v __attribute__((ext_vector_type(8)));

// ---------------- CSR build (by destination) ----------------
__global__ void count_dst_k(const int* __restrict__ ei, int* __restrict__ cnt) {
    int e = blockIdx.x * blockDim.x + threadIdx.x;
    if (e >= E_TOT) return;
    int d = (e < N_EDGES) ? ei[N_EDGES + e] : (e - N_EDGES);
    atomicAdd(&cnt[d], 1);
}

__global__ void scan_sums_k(const int* __restrict__ cnt, int* __restrict__ bsum) {
    int b = blockIdx.x;
    int start = b * CHUNK, end2 = min(start + CHUNK, N_NODES);
    int lane = threadIdx.x & 63, wv = threadIdx.x >> 6;
    int s = 0;
    for (int i = start + threadIdx.x; i < end2; i += 256) s += cnt[i];
    #pragma unroll
    for (int off = 32; off; off >>= 1) s += __shfl_xor(s, off);
    __shared__ int ws[4];
    if (lane == 0) ws[wv] = s;
    __syncthreads();
    if (threadIdx.x == 0) bsum[b] = ws[0] + ws[1] + ws[2] + ws[3];
}

__global__ void scan_off_k(int* __restrict__ bsum, int* __restrict__ row_ptr) {
    int lane = threadIdx.x;  // 64 threads
    int v = bsum[lane];
    int s = v;
    #pragma unroll
    for (int off = 1; off < 64; off <<= 1) {
        int t = __shfl_up(s, off);
        if (lane >= off) s += t;
    }
    bsum[lane] = s - v;  // exclusive
    if (lane == 63) row_ptr[N_NODES] = s;
}

__global__ void scan_write_k(const int* __restrict__ cnt, const int* __restrict__ bsum,
                             int* __restrict__ row_ptr, int* __restrict__ cursor) {
    int b = blockIdx.x;
    int start = b * CHUNK, end2 = min(start + CHUNK, N_NODES);
    __shared__ int wsum[4];
    __shared__ int carry_sh;
    int lane = threadIdx.x & 63, wv = threadIdx.x >> 6;
    if (threadIdx.x == 0) carry_sh = bsum[b];
    __syncthreads();
    for (int base = start; base < end2; base += 256) {
        int i = base + threadIdx.x;
        int v = (i < end2) ? cnt[i] : 0;
        int s = v;
        #pragma unroll
        for (int off = 1; off < 64; off <<= 1) {
            int t = __shfl_up(s, off);
            if (lane >= off) s += t;
        }
        if (lane == 63) wsum[wv] = s;
        __syncthreads();
        int woff = 0;
        #pragma unroll
        for (int k = 0; k < 4; ++k) if (k < wv) woff += wsum[k];
        int carry = carry_sh;
        if (i < end2) { int rp = carry + woff + s - v; row_ptr[i] = rp; cursor[i] = rp; }
        __syncthreads();
        if (threadIdx.x == 0) carry_sh = carry + wsum[0] + wsum[1] + wsum[2] + wsum[3];
        __syncthreads();
    }
}

__global__ void fill_k(const int* __restrict__ ei, int* __restrict__ cursor,
                       int* __restrict__ col) {
    int e = blockIdx.x * blockDim.x + threadIdx.x;
    if (e >= E_TOT) return;
    int s, d;
    if (e < N_EDGES) { s = ei[e]; d = ei[N_EDGES + e]; }
    else { s = e - N_EDGES; d = s; }
    int slot = atomicAdd(&cursor[d], 1);
    col[slot] = s;
}

// ---------------- pack W (fp32 KxNOUT) into MFMA B-fragment order, fp16 ----------------
// Wp[((tile*KS + ks)*64 + lane)*8 + j] = W[ks*32 + (lane>>4)*8 + j][tile*16 + (lane&15)]
template<int K, int NOUT>
__global__ void pack_w_k(const float* __restrict__ W, _Float16* __restrict__ Wp) {
    constexpr int total = (NOUT / 16) * (K / 32) * 64;
    int t = blockIdx.x * blockDim.x + threadIdx.x;
    if (t >= total) return;
    int lane = t & 63;
    int rest = t >> 6;
    int ks = rest % (K / 32);
    int n  = rest / (K / 32);
    int colW = n * 16 + (lane & 15);
    int krow = ks * 32 + (lane >> 4) * 8;
    h8v v;
    #pragma unroll
    for (int j = 0; j < 8; ++j) v[j] = (_Float16)W[(size_t)(krow + j) * NOUT + colW];
    *(h8v*)(Wp + (size_t)t * 8) = v;
}

// ---------------- MFMA GEMM + fused scores; emits fp16 h SLICE-MAJOR ----------------
// block = 256 = 4 waves; 64 rows/block (16 rows/wave); mfma_f32_16x16x32_f16.
// A: m=lane&15, k=quad*8+j (from LDS); B: n=lane&15, k=quad*8+j (packed Wp);
// C/D: col=lane&15, row=quad*4+reg (guide-verified, dtype-independent).
template<int K, int NOUT, typename XT>
__global__ __launch_bounds__(256) void gemm_k(const XT* __restrict__ x,
                                              const _Float16* __restrict__ Wp,
                                              const float* __restrict__ asrc,
                                              const float* __restrict__ adst,
                                              _Float16* __restrict__ outh,
                                              float* __restrict__ ssrc,
                                              float* __restrict__ sdst) {
    constexpr int SLICE = NOUT / 8;
    constexpr int Fo  = NOUT / NH;
    constexpr int FoT = Fo / 16;       // tiles per head (2 or 4)
    constexpr int KS  = K / 32;        // MFMA k-steps
    constexpr int NT  = NOUT / 16;     // col tiles
    constexpr int LK  = K + 8;         // padded halves per LDS row
    __shared__ __align__(16) _Float16 xs[64 * LK];
    int row0 = blockIdx.x * 64;
    for (int seg = threadIdx.x; seg < 64 * K / 8; seg += 256) {
        int r = seg / (K / 8);
        int c = (seg % (K / 8)) * 8;
        h8v v = {};
        if (row0 + r < N_NODES) {
            if constexpr (sizeof(XT) == 2) {
                v = *(const h8v*)((const _Float16*)x + (size_t)(row0 + r) * K + c);
            } else {
                const float* xp = (const float*)x + (size_t)(row0 + r) * K + c;
                float4 a = *(const float4*)xp;
                float4 b = *(const float4*)(xp + 4);
                v[0] = (_Float16)a.x; v[1] = (_Float16)a.y;
                v[2] = (_Float16)a.z; v[3] = (_Float16)a.w;
                v[4] = (_Float16)b.x; v[5] = (_Float16)b.y;
                v[6] = (_Float16)b.z; v[7] = (_Float16)b.w;
            }
        }
        *(h8v*)(xs + r * LK + c) = v;
    }
    __syncthreads();
    int wv = threadIdx.x >> 6, lane = threadIdx.x & 63;
    int quad = lane >> 4, colL = lane & 15;
    int r0 = row0 + wv * 16;
    h8v afr[KS];
    #pragma unroll
    for (int ks = 0; ks < KS; ++ks)
        afr[ks] = *(const h8v*)(xs + (wv * 16 + colL) * LK + ks * 32 + quad * 8);
    const h8v* bp = (const h8v*)Wp;
    float psa[4] = {0.f, 0.f, 0.f, 0.f}, pda[4] = {0.f, 0.f, 0.f, 0.f};
    #pragma unroll
    for (int t = 0; t < NT; ++t) {
        v4f acc = {};
        #pragma unroll
        for (int ks = 0; ks < KS; ++ks) {
            h8v bfr = bp[(size_t)(t * KS + ks) * 64 + lane];
            acc = __builtin_amdgcn_mfma_f32_16x16x32_f16(afr[ks], bfr, acc, 0, 0, 0);
        }
        int n0 = t * 16;
        int col = n0 + colL;
        float as_ = asrc[col], ad_ = adst[col];
        int sl = n0 / SLICE;            // 16-col tile lies inside one slice
        int so = col % SLICE;
        _Float16* op = outh + (size_t)sl * N_NODES * SLICE + so;
        #pragma unroll
        for (int reg = 0; reg < 4; ++reg) {
            int row = r0 + quad * 4 + reg;
            float cv = acc[reg];
            if (row < N_NODES) op[(size_t)row * SLICE] = (_Float16)cv;
            float ps = cv * as_, pd = cv * ad_;
            #pragma unroll
            for (int off = 1; off < 16; off <<= 1) {
                ps += __shfl_xor(ps, off);
                pd += __shfl_xor(pd, off);
            }
            psa[reg] += ps; pda[reg] += pd;
        }
        if ((t & (FoT - 1)) == (FoT - 1)) {
            int hd = t / FoT;
            if (colL == 0) {
                #pragma unroll
                for (int reg = 0; reg < 4; ++reg) {
                    int row = r0 + quad * 4 + reg;
                    if (row < N_NODES) {
                        ssrc[row * NH + hd] = psa[reg];
                        sdst[row * NH + hd] = pda[reg];
                    }
                }
            }
            #pragma unroll
            for (int reg = 0; reg < 4; ++reg) { psa[reg] = 0.f; pda[reg] = 0.f; }
        }
    }
}

// ---------------- normalized softmax weights -> per-head PLANES ----------------
__global__ __launch_bounds__(256) void alpha_k(const float* __restrict__ ssrc,
                                               const float* __restrict__ sdst,
                                               const int* __restrict__ row_ptr,
                                               const int* __restrict__ col,
                                               float* __restrict__ alpha) {
    int wv = threadIdx.x >> 6, lane = threadIdx.x & 63;
    int v = blockIdx.x * 4 + wv;
    if (v >= N_NODES) return;
    int hd = lane >> 4, lg = lane & 15;
    int beg = row_ptr[v], cnt = row_ptr[v + 1] - beg;
    float sdv = sdst[v * NH + hd];
    float* pl = alpha + (size_t)hd * E_TOT + beg;

    if (cnt <= 128) {
        float er[8];
        float m = -FLT_MAX;
        #pragma unroll
        for (int i = 0; i < 8; ++i) {
            int j = lg + i * 16;
            if (j < cnt) {
                int u = col[beg + j];
                float e = ssrc[u * NH + hd] + sdv;
                e = (e > 0.f) ? e : 0.2f * e;
                er[i] = e;
                m = fmaxf(m, e);
            }
        }
        #pragma unroll
        for (int off = 1; off < 16; off <<= 1) m = fmaxf(m, __shfl_xor(m, off));
        float den = 0.f;
        #pragma unroll
        for (int i = 0; i < 8; ++i) {
            int j = lg + i * 16;
            if (j < cnt) { float w = __expf(er[i] - m); er[i] = w; den += w; }
        }
        #pragma unroll
        for (int off = 1; off < 16; off <<= 1) den += __shfl_xor(den, off);
        float inv = 1.f / (den + 1e-16f);
        #pragma unroll
        for (int i = 0; i < 8; ++i) {
            int j = lg + i * 16;
            if (j < cnt) pl[j] = er[i] * inv;
        }
    } else {
        float m = -FLT_MAX;
        for (int j = lg; j < cnt; j += 16) {
            int u = col[beg + j];
            float e = ssrc[u * NH + hd] + sdv;
            e = (e > 0.f) ? e : 0.2f * e;
            m = fmaxf(m, e);
        }
        #pragma unroll
        for (int off = 1; off < 16; off <<= 1) m = fmaxf(m, __shfl_xor(m, off));
        float den = 0.f;
        for (int j = lg; j < cnt; j += 16) {
            int u = col[beg + j];
            float e = ssrc[u * NH + hd] + sdv;
            e = (e > 0.f) ? e : 0.2f * e;
            den += __expf(e - m);
        }
        #pragma unroll
        for (int off = 1; off < 16; off <<= 1) den += __shfl_xor(den, off);
        float inv = 1.f / (den + 1e-16f);
        for (int j = lg; j < cnt; j += 16) {
            int u = col[beg + j];
            float e = ssrc[u * NH + hd] + sdv;
            e = (e > 0.f) ? e : 0.2f * e;
            pl[j] = __expf(e - m) * inv;
        }
    }
}

// ---------------- XCD-sharded aggregation, wave-span LDS staging ----------------
template<int HFo, int SLICE, int LPN>
__global__ __launch_bounds__(256) void agg3_k(const _Float16* __restrict__ hh,
                                              const float* __restrict__ alpha,
                                              const int* __restrict__ row_ptr,
                                              const int* __restrict__ col,
                                              const float* __restrict__ bias,
                                              _Float16* __restrict__ outH) {
    constexpr int Fo   = HFo / NH;
    constexpr int NPW  = 64 / LPN;    // nodes per wave
    constexpr int NPB  = 4 * NPW;     // nodes per block
    constexpr int CAPW = NPW * 32;    // span capacity
    __shared__ int   colS[4][CAPW];
    __shared__ float awS[4][CAPW];
    int s = blockIdx.x & 7;
    int g = blockIdx.x >> 3;
    int wv = threadIdx.x >> 6, lane = threadIdx.x & 63;
    int sub = lane / LPN, lq = lane % LPN;
    int vFirst = g * NPB + wv * NPW;
    if (vFirst >= N_NODES) return;
    int vCount = min(NPW, N_NODES - vFirst);
    int hd = (s * SLICE) / Fo;
    const float* ap = alpha + (size_t)hd * E_TOT;
    int begW = row_ptr[vFirst];
    int endW = row_ptr[vFirst + vCount];
    int len = endW - begW;
    bool active = sub < vCount;
    int v = vFirst + sub;
    int beg = 0, cnt = 0;
    if (active) { beg = row_ptr[v]; cnt = row_ptr[v + 1] - beg; }
    const _Float16* hp = hh + (size_t)s * N_NODES * SLICE + lq * 8;
    float acc[8] = {};

    if (len <= CAPW) {
        for (int t = lane; t < len; t += 64) {
            colS[wv][t] = col[begW + t];
            awS[wv][t]  = ap[begW + t];
        }
        __builtin_amdgcn_wave_barrier();
        int off = beg - begW;
        int j = 0;
        for (; j + 8 <= cnt; j += 8) {
            int u[8]; float w[8]; h8v hv[8];
            #pragma unroll
            for (int i = 0; i < 8; ++i) { u[i] = colS[wv][off + j + i]; w[i] = awS[wv][off + j + i]; }
            #pragma unroll
            for (int i = 0; i < 8; ++i) hv[i] = *(const h8v*)(hp + (size_t)u[i] * SLICE);
            #pragma unroll
            for (int i = 0; i < 8; ++i)
                #pragma unroll
                for (int c = 0; c < 8; ++c) acc[c] += w[i] * (float)hv[i][c];
        }
        for (; j < cnt; ++j) {
            int u = colS[wv][off + j];
            float w = awS[wv][off + j];
            h8v hv = *(const h8v*)(hp + (size_t)u * SLICE);
            #pragma unroll
            for (int c = 0; c < 8; ++c) acc[c] += w * (float)hv[c];
        }
    } else {
        const int*   cp = col + beg;
        const float* app = ap + beg;
        for (int j = 0; j < cnt; ++j) {
            int u = cp[j];
            float w = app[j];
            h8v hv = *(const h8v*)(hp + (size_t)u * SLICE);
            #pragma unroll
            for (int c = 0; c < 8; ++c) acc[c] += w * (float)hv[c];
        }
    }
    if (active) {
        int f0 = s * SLICE + lq * 8;
        h8v res;
        #pragma unroll
        for (int c = 0; c < 8; ++c) res[c] = (_Float16)fmaxf(acc[c] + bias[f0 + c], 0.f);
        *(h8v*)(outH + (size_t)v * HFo + f0) = res;
    }
}

// ---------------- pooling (fp16 input; batch sorted -> run-length pre-agg) ----------------
__global__ void pool_k(const _Float16* __restrict__ h, const int* __restrict__ batch,
                       float* __restrict__ gsum, float* __restrict__ gmax) {
    int f = threadIdx.x;  // 256
    int n0 = blockIdx.x * 32;
    int nend = min(n0 + 32, N_NODES);
    int cur = -1;
    float sa = 0.f, ma = 0.f;
    for (int n = n0; n < nend; ++n) {
        int g = batch[n];
        float val = (float)h[(size_t)n * 256 + f];
        if (g != cur) {
            if (cur >= 0) {
                atomicAdd(&gsum[cur * 256 + f], sa);
                atomicMax((int*)&gmax[cur * 256 + f], __float_as_int(ma));
            }
            cur = g; sa = 0.f; ma = 0.f;
        }
        sa += val;
        ma = fmaxf(ma, val);
    }
    if (cur >= 0) {
        atomicAdd(&gsum[cur * 256 + f], sa);
        atomicMax((int*)&gmax[cur * 256 + f], __float_as_int(ma));
    }
}

__global__ void gcnt_k(const int* __restrict__ batch, int* __restrict__ gcnt) {
    int g = threadIdx.x;  // 128 threads
    if (g >= NG) return;
    int lo = 0, hi = N_NODES;
    while (lo < hi) { int mid = (lo + hi) >> 1; if (batch[mid] < g) lo = mid + 1; else hi = mid; }
    int b0 = lo;
    lo = 0; hi = N_NODES;
    while (lo < hi) { int mid = (lo + hi) >> 1; if (batch[mid] < g + 1) lo = mid + 1; else hi = mid; }
    gcnt[g] = lo - b0;
}

__global__ void readout_k(const float* __restrict__ gsum, const float* __restrict__ gmax,
                          const int* __restrict__ gcnt, const float* __restrict__ Wout,
                          const float* __restrict__ bout, float* __restrict__ out) {
    int g = blockIdx.x, lane = threadIdx.x;
    float inv = 1.f / fmaxf((float)gcnt[g], 1.f);
    float acc[10];
    #pragma unroll
    for (int j = 0; j < 10; ++j) acc[j] = 0.f;
    for (int f = lane; f < 512; f += 64) {
        float p = (f < 256) ? gsum[g * 256 + f] * inv : gmax[g * 256 + (f - 256)];
        #pragma unroll
        for (int j = 0; j < 10; ++j) acc[j] += p * Wout[f * 10 + j];
    }
    #pragma unroll
    for (int j = 0; j < 10; ++j) {
        float a = acc[j];
        #pragma unroll
        for (int off = 32; off; off >>= 1) a += __shfl_xor(a, off);
        if (lane == 0) out[g * 10 + j] = a + bout[j];
    }
}

extern "C" void kernel_launch(void* const* d_in, const int* in_sizes, int n_in,
                              void* d_out, int out_size, void* d_ws, size_t ws_size,
                              hipStream_t stream) {
    const float* x    = (const float*)d_in[0];
    const int*   ei   = (const int*)d_in[1];
    const int*   batch= (const int*)d_in[2];
    const float* W0   = (const float*)d_in[3];
    const float* as0  = (const float*)d_in[4];
    const float* ad0  = (const float*)d_in[5];
    const float* b0   = (const float*)d_in[6];
    const float* W1   = (const float*)d_in[7];
    const float* as1  = (const float*)d_in[8];
    const float* ad1  = (const float*)d_in[9];
    const float* b1   = (const float*)d_in[10];
    const float* W2   = (const float*)d_in[11];
    const float* as2  = (const float*)d_in[12];
    const float* ad2  = (const float*)d_in[13];
    const float* b2   = (const float*)d_in[14];
    const float* Wout = (const float*)d_in[15];
    const float* bout = (const float*)d_in[16];
    float* out = (float*)d_out;

    char* ws = (char*)d_ws;
    size_t o = 0;
    auto take = [&](size_t bytes) { size_t r = o; o += (bytes + 255) & ~(size_t)255; return r; };
    size_t cnt_o  = take((size_t)N_NODES * 4);
    size_t gsum_o = take((size_t)NG * 256 * 4);
    size_t gmax_o = take((size_t)NG * 256 * 4);
    size_t gcnt_o = take((size_t)NG * 4);
    size_t zero_bytes = o;
    size_t rp_o   = take((size_t)(N_NODES + 1) * 4);
    size_t cur_o  = take((size_t)N_NODES * 4);
    size_t bsum_o = take((size_t)64 * 4);
    size_t col_o  = take((size_t)E_TOT * 4);
    size_t ssrc_o = take((size_t)N_NODES * NH * 4);
    size_t sdst_o = take((size_t)N_NODES * NH * 4);
    size_t alp_o  = take((size_t)NH * E_TOT * 4);      // per-head alpha planes
    size_t hh_o   = take((size_t)N_NODES * 256 * 2);   // fp16 h slice-major (gather)
    size_t bufH_o = take((size_t)N_NODES * 256 * 2);   // fp16 h row-major (gemm/pool in)
    size_t wp0_o  = take((size_t)128 * 128 * 2);       // packed fp16 weights
    size_t wp1_o  = take((size_t)128 * 256 * 2);
    size_t wp2_o  = take((size_t)256 * 256 * 2);

    int*      cnt    = (int*)(ws + cnt_o);
    float*    gsum   = (float*)(ws + gsum_o);
    float*    gmax   = (float*)(ws + gmax_o);
    int*      gcnt   = (int*)(ws + gcnt_o);
    int*      row_ptr= (int*)(ws + rp_o);
    int*      cursor = (int*)(ws + cur_o);
    int*      bsum   = (int*)(ws + bsum_o);
    int*      col    = (int*)(ws + col_o);
    float*    ssrc   = (float*)(ws + ssrc_o);
    float*    sdst   = (float*)(ws + sdst_o);
    float*    alpha  = (float*)(ws + alp_o);
    _Float16* hH     = (_Float16*)(ws + hh_o);
    _Float16* bufH   = (_Float16*)(ws + bufH_o);
    _Float16* Wp0    = (_Float16*)(ws + wp0_o);
    _Float16* Wp1    = (_Float16*)(ws + wp1_o);
    _Float16* Wp2    = (_Float16*)(ws + wp2_o);

    (void)hipMemsetAsync(ws, 0, zero_bytes, stream);

    count_dst_k<<<(E_TOT + 255) / 256, 256, 0, stream>>>(ei, cnt);
    scan_sums_k<<<64, 256, 0, stream>>>(cnt, bsum);
    scan_off_k<<<1, 64, 0, stream>>>(bsum, row_ptr);
    scan_write_k<<<64, 256, 0, stream>>>(cnt, bsum, row_ptr, cursor);
    fill_k<<<(E_TOT + 255) / 256, 256, 0, stream>>>(ei, cursor, col);

    // weight packing (tiny; overlaps CSR build in HW)
    pack_w_k<128, 128><<<8, 256, 0, stream>>>(W0, Wp0);
    pack_w_k<128, 256><<<16, 256, 0, stream>>>(W1, Wp1);
    pack_w_k<256, 256><<<32, 256, 0, stream>>>(W2, Wp2);

    int gemm_grid  = (N_NODES + 63) / 64;
    int alpha_grid = (N_NODES + 3) / 4;
    int agg128_grid = 8 * ((N_NODES + 127) / 128);
    int agg256_grid = 8 * ((N_NODES + 63) / 64);

    // layer 0: 128 -> H4*Fo32 (128)
    gemm_k<128, 128, float><<<gemm_grid, 256, 0, stream>>>(x, Wp0, as0, ad0, hH, ssrc, sdst);
    alpha_k<<<alpha_grid, 256, 0, stream>>>(ssrc, sdst, row_ptr, col, alpha);
    agg3_k<128, 16, 2><<<agg128_grid, 256, 0, stream>>>(hH, alpha, row_ptr, col, b0, bufH);

    // layer 1: 128 -> H4*Fo64 (256)
    gemm_k<128, 256, _Float16><<<gemm_grid, 256, 0, stream>>>(bufH, Wp1, as1, ad1, hH, ssrc, sdst);
    alpha_k<<<alpha_grid, 256, 0, stream>>>(ssrc, sdst, row_ptr, col, alpha);
    agg3_k<256, 32, 4><<<agg256_grid, 256, 0, stream>>>(hH, alpha, row_ptr, col, b1, bufH);

    // layer 2: 256 -> H4*Fo64 (256)
    gemm_k<256, 256, _Float16><<<gemm_grid, 256, 0, stream>>>(bufH, Wp2, as2, ad2, hH, ssrc, sdst);
    alpha_k<<<alpha_grid, 256, 0, stream>>>(ssrc, sdst, row_ptr, col, alpha);
    agg3_k<256, 32, 4><<<agg256_grid, 256, 0, stream>>>(hH, alpha, row_ptr, col, b2, bufH);

    // pooling + readout
    pool_k<<<(N_NODES + 31) / 32, 256, 0, stream>>>(bufH, batch, gsum, gmax);
    gcnt_k<<<1, 128, 0, stream>>>(batch, gcnt);
    readout_k<<<NG, 64, 0, stream>>>(gsum, gmax, gcnt, Wout, bout, out);
}

// Round 12
// 525.849 us; speedup vs baseline: 1.7448x; 1.0139x over previous
//
#include <hip/hip_runtime.h>
#include <cfloat>

#define N_NODES 50000
#define N_EDGES 800000
#define E_TOT   850000
#define NG      128
#define NH      4
#define CHUNK   782   // ceil(N_NODES/64) for the 64-block scan

typedef float f4 __attribute__((ext_vector_type(4)));
typedef float v4f __attribute__((ext_vector_type(4)));
typedef _Float16 h8v __attribute__((ext_vector_type(8)));

// ---------------- CSR build (by destination) ----------------
__global__ void count_dst_k(const int* __restrict__ ei, int* __restrict__ cnt) {
    int e = blockIdx.x * blockDim.x + threadIdx.x;
    if (e >= E_TOT) return;
    int d = (e < N_EDGES) ? ei[N_EDGES + e] : (e - N_EDGES);
    atomicAdd(&cnt[d], 1);
}

__global__ void scan_sums_k(const int* __restrict__ cnt, int* __restrict__ bsum) {
    int b = blockIdx.x;
    int start = b * CHUNK, end2 = min(start + CHUNK, N_NODES);
    int lane = threadIdx.x & 63, wv = threadIdx.x >> 6;
    int s = 0;
    for (int i = start + threadIdx.x; i < end2; i += 256) s += cnt[i];
    #pragma unroll
    for (int off = 32; off; off >>= 1) s += __shfl_xor(s, off);
    __shared__ int ws[4];
    if (lane == 0) ws[wv] = s;
    __syncthreads();
    if (threadIdx.x == 0) bsum[b] = ws[0] + ws[1] + ws[2] + ws[3];
}

__global__ void scan_off_k(int* __restrict__ bsum, int* __restrict__ row_ptr) {
    int lane = threadIdx.x;  // 64 threads
    int v = bsum[lane];
    int s = v;
    #pragma unroll
    for (int off = 1; off < 64; off <<= 1) {
        int t = __shfl_up(s, off);
        if (lane >= off) s += t;
    }
    bsum[lane] = s - v;  // exclusive
    if (lane == 63) row_ptr[N_NODES] = s;
}

__global__ void scan_write_k(const int* __restrict__ cnt, const int* __restrict__ bsum,
                             int* __restrict__ row_ptr, int* __restrict__ cursor) {
    int b = blockIdx.x;
    int start = b * CHUNK, end2 = min(start + CHUNK, N_NODES);
    __shared__ int wsum[4];
    __shared__ int carry_sh;
    int lane = threadIdx.x & 63, wv = threadIdx.x >> 6;
    if (threadIdx.x == 0) carry_sh = bsum[b];
    __syncthreads();
    for (int base = start; base < end2; base += 256) {
        int i = base + threadIdx.x;
        int v = (i < end2) ? cnt[i] : 0;
        int s = v;
        #pragma unroll
        for (int off = 1; off < 64; off <<= 1) {
            int t = __shfl_up(s, off);
            if (lane >= off) s += t;
        }
        if (lane == 63) wsum[wv] = s;
        __syncthreads();
        int woff = 0;
        #pragma unroll
        for (int k = 0; k < 4; ++k) if (k < wv) woff += wsum[k];
        int carry = carry_sh;
        if (i < end2) { int rp = carry + woff + s - v; row_ptr[i] = rp; cursor[i] = rp; }
        __syncthreads();
        if (threadIdx.x == 0) carry_sh = carry + wsum[0] + wsum[1] + wsum[2] + wsum[3];
        __syncthreads();
    }
}

__global__ void fill_k(const int* __restrict__ ei, int* __restrict__ cursor,
                       int* __restrict__ col) {
    int e = blockIdx.x * blockDim.x + threadIdx.x;
    if (e >= E_TOT) return;
    int s, d;
    if (e < N_EDGES) { s = ei[e]; d = ei[N_EDGES + e]; }
    else { s = e - N_EDGES; d = s; }
    int slot = atomicAdd(&cursor[d], 1);
    col[slot] = s;
}

// ---------------- pack W (fp32 KxNOUT) into MFMA B-fragment order, fp16 ----------------
// Wp[((tile*KS + ks)*64 + lane)*8 + j] = W[ks*32 + (lane>>4)*8 + j][tile*16 + (lane&15)]
template<int K, int NOUT>
__global__ void pack_w_k(const float* __restrict__ W, _Float16* __restrict__ Wp) {
    constexpr int total = (NOUT / 16) * (K / 32) * 64;
    int t = blockIdx.x * blockDim.x + threadIdx.x;
    if (t >= total) return;
    int lane = t & 63;
    int rest = t >> 6;
    int ks = rest % (K / 32);
    int n  = rest / (K / 32);
    int colW = n * 16 + (lane & 15);
    int krow = ks * 32 + (lane >> 4) * 8;
    h8v v;
    #pragma unroll
    for (int j = 0; j < 8; ++j) v[j] = (_Float16)W[(size_t)(krow + j) * NOUT + colW];
    *(h8v*)(Wp + (size_t)t * 8) = v;
}

// ---------------- fold a_src/a_dst into the extra score tile (tile NT) ----------------
// col 0..3 = wsrc[k][h]; col 4..7 = wdst[k][h]; col 8..15 = 0.
template<int K, int NOUT>
__global__ void pack_a_k(const float* __restrict__ W, const float* __restrict__ asrc,
                         const float* __restrict__ adst, _Float16* __restrict__ Wp) {
    constexpr int KS = K / 32;
    constexpr int NT = NOUT / 16;
    constexpr int Fo = NOUT / NH;
    int t = blockIdx.x * blockDim.x + threadIdx.x;
    if (t >= KS * 64) return;
    int ks = t >> 6, lane = t & 63;
    int colL = lane & 15;
    int krow = ks * 32 + ((lane >> 4) & 3) * 8;
    h8v v = {};
    if (colL < 8) {
        int hd = colL & 3;
        const float* av = (colL < 4) ? asrc : adst;
        #pragma unroll
        for (int j = 0; j < 8; ++j) {
            float s = 0.f;
            const float* wr = W + (size_t)(krow + j) * NOUT + hd * Fo;
            for (int f = 0; f < Fo; ++f) s += wr[f] * av[hd * Fo + f];
            v[j] = (_Float16)s;
        }
    }
    *(h8v*)(Wp + (size_t)((NT * KS + ks) * 64 + lane) * 8) = v;
}

// ---------------- MFMA GEMM; h slice-major fp16 + scores via folded tile ----------------
// block = 256 = 4 waves; 64 rows/block (16 rows/wave); mfma_f32_16x16x32_f16.
// A: m=lane&15, k=quad*8+j (LDS); B: n=lane&15, k=quad*8+j (packed Wp);
// C/D: col=lane&15, row=quad*4+reg.
template<int K, int NOUT, typename XT>
__global__ __launch_bounds__(256) void gemm_k(const XT* __restrict__ x,
                                              const _Float16* __restrict__ Wp,
                                              _Float16* __restrict__ outh,
                                              float* __restrict__ ssrc,
                                              float* __restrict__ sdst) {
    constexpr int SLICE = NOUT / 8;
    constexpr int KS  = K / 32;        // MFMA k-steps
    constexpr int NT  = NOUT / 16;     // h col tiles (score tile is NT)
    constexpr int LK  = K + 8;         // padded halves per LDS row
    __shared__ __align__(16) _Float16 xs[64 * LK];
    int row0 = blockIdx.x * 64;
    for (int seg = threadIdx.x; seg < 64 * K / 8; seg += 256) {
        int r = seg / (K / 8);
        int c = (seg % (K / 8)) * 8;
        h8v v = {};
        if (row0 + r < N_NODES) {
            if constexpr (sizeof(XT) == 2) {
                v = *(const h8v*)((const _Float16*)x + (size_t)(row0 + r) * K + c);
            } else {
                const float* xp = (const float*)x + (size_t)(row0 + r) * K + c;
                float4 a = *(const float4*)xp;
                float4 b = *(const float4*)(xp + 4);
                v[0] = (_Float16)a.x; v[1] = (_Float16)a.y;
                v[2] = (_Float16)a.z; v[3] = (_Float16)a.w;
                v[4] = (_Float16)b.x; v[5] = (_Float16)b.y;
                v[6] = (_Float16)b.z; v[7] = (_Float16)b.w;
            }
        }
        *(h8v*)(xs + r * LK + c) = v;
    }
    __syncthreads();
    int wv = threadIdx.x >> 6, lane = threadIdx.x & 63;
    int quad = lane >> 4, colL = lane & 15;
    int r0 = row0 + wv * 16;
    h8v afr[KS];
    #pragma unroll
    for (int ks = 0; ks < KS; ++ks)
        afr[ks] = *(const h8v*)(xs + (wv * 16 + colL) * LK + ks * 32 + quad * 8);
    const h8v* bp = (const h8v*)Wp;
    #pragma unroll
    for (int t = 0; t <= NT; ++t) {
        v4f acc = {};
        #pragma unroll
        for (int ks = 0; ks < KS; ++ks) {
            h8v bfr = bp[(size_t)(t * KS + ks) * 64 + lane];
            acc = __builtin_amdgcn_mfma_f32_16x16x32_f16(afr[ks], bfr, acc, 0, 0, 0);
        }
        if (t < NT) {
            int n0 = t * 16;
            int col = n0 + colL;
            int sl = n0 / SLICE;
            int so = col % SLICE;
            _Float16* op = outh + (size_t)sl * N_NODES * SLICE + so;
            #pragma unroll
            for (int reg = 0; reg < 4; ++reg) {
                int row = r0 + quad * 4 + reg;
                if (row < N_NODES) op[(size_t)row * SLICE] = (_Float16)acc[reg];
            }
        } else if (colL < 8) {
            int hd = colL & 3;
            float* sp = (colL < 4) ? ssrc : sdst;
            #pragma unroll
            for (int reg = 0; reg < 4; ++reg) {
                int row = r0 + quad * 4 + reg;
                if (row < N_NODES) sp[row * NH + hd] = acc[reg];
            }
        }
    }
}

// ---------------- normalized softmax weights -> per-head PLANES ----------------
__global__ __launch_bounds__(256) void alpha_k(const float* __restrict__ ssrc,
                                               const float* __restrict__ sdst,
                                               const int* __restrict__ row_ptr,
                                               const int* __restrict__ col,
                                               float* __restrict__ alpha) {
    int wv = threadIdx.x >> 6, lane = threadIdx.x & 63;
    int v = blockIdx.x * 4 + wv;
    if (v >= N_NODES) return;
    int hd = lane >> 4, lg = lane & 15;
    int beg = row_ptr[v], cnt = row_ptr[v + 1] - beg;
    float sdv = sdst[v * NH + hd];
    float* pl = alpha + (size_t)hd * E_TOT + beg;

    if (cnt <= 128) {
        float er[8];
        float m = -FLT_MAX;
        #pragma unroll
        for (int i = 0; i < 8; ++i) {
            int j = lg + i * 16;
            if (j < cnt) {
                int u = col[beg + j];
                float e = ssrc[u * NH + hd] + sdv;
                e = (e > 0.f) ? e : 0.2f * e;
                er[i] = e;
                m = fmaxf(m, e);
            }
        }
        #pragma unroll
        for (int off = 1; off < 16; off <<= 1) m = fmaxf(m, __shfl_xor(m, off));
        float den = 0.f;
        #pragma unroll
        for (int i = 0; i < 8; ++i) {
            int j = lg + i * 16;
            if (j < cnt) { float w = __expf(er[i] - m); er[i] = w; den += w; }
        }
        #pragma unroll
        for (int off = 1; off < 16; off <<= 1) den += __shfl_xor(den, off);
        float inv = 1.f / (den + 1e-16f);
        #pragma unroll
        for (int i = 0; i < 8; ++i) {
            int j = lg + i * 16;
            if (j < cnt) pl[j] = er[i] * inv;
        }
    } else {
        float m = -FLT_MAX;
        for (int j = lg; j < cnt; j += 16) {
            int u = col[beg + j];
            float e = ssrc[u * NH + hd] + sdv;
            e = (e > 0.f) ? e : 0.2f * e;
            m = fmaxf(m, e);
        }
        #pragma unroll
        for (int off = 1; off < 16; off <<= 1) m = fmaxf(m, __shfl_xor(m, off));
        float den = 0.f;
        for (int j = lg; j < cnt; j += 16) {
            int u = col[beg + j];
            float e = ssrc[u * NH + hd] + sdv;
            e = (e > 0.f) ? e : 0.2f * e;
            den += __expf(e - m);
        }
        #pragma unroll
        for (int off = 1; off < 16; off <<= 1) den += __shfl_xor(den, off);
        float inv = 1.f / (den + 1e-16f);
        for (int j = lg; j < cnt; j += 16) {
            int u = col[beg + j];
            float e = ssrc[u * NH + hd] + sdv;
            e = (e > 0.f) ? e : 0.2f * e;
            pl[j] = __expf(e - m) * inv;
        }
    }
}

// ---------------- XCD-sharded aggregation, wave-span LDS staging ----------------
template<int HFo, int SLICE, int LPN>
__global__ __launch_bounds__(256) void agg3_k(const _Float16* __restrict__ hh,
                                              const float* __restrict__ alpha,
                                              const int* __restrict__ row_ptr,
                                              const int* __restrict__ col,
                                              const float* __restrict__ bias,
                                              _Float16* __restrict__ outH) {
    constexpr int Fo   = HFo / NH;
    constexpr int NPW  = 64 / LPN;    // nodes per wave
    constexpr int NPB  = 4 * NPW;     // nodes per block
    constexpr int CAPW = NPW * 32;    // span capacity
    __shared__ int   colS[4][CAPW];
    __shared__ float awS[4][CAPW];
    int s = blockIdx.x & 7;
    int g = blockIdx.x >> 3;
    int wv = threadIdx.x >> 6, lane = threadIdx.x & 63;
    int sub = lane / LPN, lq = lane % LPN;
    int vFirst = g * NPB + wv * NPW;
    if (vFirst >= N_NODES) return;
    int vCount = min(NPW, N_NODES - vFirst);
    int hd = (s * SLICE) / Fo;
    const float* ap = alpha + (size_t)hd * E_TOT;
    int begW = row_ptr[vFirst];
    int endW = row_ptr[vFirst + vCount];
    int len = endW - begW;
    bool active = sub < vCount;
    int v = vFirst + sub;
    int beg = 0, cnt = 0;
    if (active) { beg = row_ptr[v]; cnt = row_ptr[v + 1] - beg; }
    const _Float16* hp = hh + (size_t)s * N_NODES * SLICE + lq * 8;
    float acc[8] = {};

    if (len <= CAPW) {
        for (int t = lane; t < len; t += 64) {
            colS[wv][t] = col[begW + t];
            awS[wv][t]  = ap[begW + t];
        }
        __builtin_amdgcn_wave_barrier();
        int off = beg - begW;
        int j = 0;
        for (; j + 8 <= cnt; j += 8) {
            int u[8]; float w[8]; h8v hv[8];
            #pragma unroll
            for (int i = 0; i < 8; ++i) { u[i] = colS[wv][off + j + i]; w[i] = awS[wv][off + j + i]; }
            #pragma unroll
            for (int i = 0; i < 8; ++i) hv[i] = *(const h8v*)(hp + (size_t)u[i] * SLICE);
            #pragma unroll
            for (int i = 0; i < 8; ++i)
                #pragma unroll
                for (int c = 0; c < 8; ++c) acc[c] += w[i] * (float)hv[i][c];
        }
        for (; j < cnt; ++j) {
            int u = colS[wv][off + j];
            float w = awS[wv][off + j];
            h8v hv = *(const h8v*)(hp + (size_t)u * SLICE);
            #pragma unroll
            for (int c = 0; c < 8; ++c) acc[c] += w * (float)hv[c];
        }
    } else {
        const int*   cp = col + beg;
        const float* app = ap + beg;
        for (int j = 0; j < cnt; ++j) {
            int u = cp[j];
            float w = app[j];
            h8v hv = *(const h8v*)(hp + (size_t)u * SLICE);
            #pragma unroll
            for (int c = 0; c < 8; ++c) acc[c] += w * (float)hv[c];
        }
    }
    if (active) {
        int f0 = s * SLICE + lq * 8;
        h8v res;
        #pragma unroll
        for (int c = 0; c < 8; ++c) res[c] = (_Float16)fmaxf(acc[c] + bias[f0 + c], 0.f);
        *(h8v*)(outH + (size_t)v * HFo + f0) = res;
    }
}

// ---------------- pooling (fp16 input; batch sorted -> run-length pre-agg) ----------------
__global__ void pool_k(const _Float16* __restrict__ h, const int* __restrict__ batch,
                       float* __restrict__ gsum, float* __restrict__ gmax) {
    int f = threadIdx.x;  // 256
    int n0 = blockIdx.x * 32;
    int nend = min(n0 + 32, N_NODES);
    int cur = -1;
    float sa = 0.f, ma = 0.f;
    for (int n = n0; n < nend; ++n) {
        int g = batch[n];
        float val = (float)h[(size_t)n * 256 + f];
        if (g != cur) {
            if (cur >= 0) {
                atomicAdd(&gsum[cur * 256 + f], sa);
                atomicMax((int*)&gmax[cur * 256 + f], __float_as_int(ma));
            }
            cur = g; sa = 0.f; ma = 0.f;
        }
        sa += val;
        ma = fmaxf(ma, val);
    }
    if (cur >= 0) {
        atomicAdd(&gsum[cur * 256 + f], sa);
        atomicMax((int*)&gmax[cur * 256 + f], __float_as_int(ma));
    }
}

__global__ void gcnt_k(const int* __restrict__ batch, int* __restrict__ gcnt) {
    int g = threadIdx.x;  // 128 threads
    if (g >= NG) return;
    int lo = 0, hi = N_NODES;
    while (lo < hi) { int mid = (lo + hi) >> 1; if (batch[mid] < g) lo = mid + 1; else hi = mid; }
    int b0 = lo;
    lo = 0; hi = N_NODES;
    while (lo < hi) { int mid = (lo + hi) >> 1; if (batch[mid] < g + 1) lo = mid + 1; else hi = mid; }
    gcnt[g] = lo - b0;
}

__global__ void readout_k(const float* __restrict__ gsum, const float* __restrict__ gmax,
                          const int* __restrict__ gcnt, const float* __restrict__ Wout,
                          const float* __restrict__ bout, float* __restrict__ out) {
    int g = blockIdx.x, lane = threadIdx.x;
    float inv = 1.f / fmaxf((float)gcnt[g], 1.f);
    float acc[10];
    #pragma unroll
    for (int j = 0; j < 10; ++j) acc[j] = 0.f;
    for (int f = lane; f < 512; f += 64) {
        float p = (f < 256) ? gsum[g * 256 + f] * inv : gmax[g * 256 + (f - 256)];
        #pragma unroll
        for (int j = 0; j < 10; ++j) acc[j] += p * Wout[f * 10 + j];
    }
    #pragma unroll
    for (int j = 0; j < 10; ++j) {
        float a = acc[j];
        #pragma unroll
        for (int off = 32; off; off >>= 1) a += __shfl_xor(a, off);
        if (lane == 0) out[g * 10 + j] = a + bout[j];
    }
}

extern "C" void kernel_launch(void* const* d_in, const int* in_sizes, int n_in,
                              void* d_out, int out_size, void* d_ws, size_t ws_size,
                              hipStream_t stream) {
    const float* x    = (const float*)d_in[0];
    const int*   ei   = (const int*)d_in[1];
    const int*   batch= (const int*)d_in[2];
    const float* W0   = (const float*)d_in[3];
    const float* as0  = (const float*)d_in[4];
    const float* ad0  = (const float*)d_in[5];
    const float* b0   = (const float*)d_in[6];
    const float* W1   = (const float*)d_in[7];
    const float* as1  = (const float*)d_in[8];
    const float* ad1  = (const float*)d_in[9];
    const float* b1   = (const float*)d_in[10];
    const float* W2   = (const float*)d_in[11];
    const float* as2  = (const float*)d_in[12];
    const float* ad2  = (const float*)d_in[13];
    const float* b2   = (const float*)d_in[14];
    const float* Wout = (const float*)d_in[15];
    const float* bout = (const float*)d_in[16];
    float* out = (float*)d_out;

    char* ws = (char*)d_ws;
    size_t o = 0;
    auto take = [&](size_t bytes) { size_t r = o; o += (bytes + 255) & ~(size_t)255; return r; };
    size_t cnt_o  = take((size_t)N_NODES * 4);
    size_t gsum_o = take((size_t)NG * 256 * 4);
    size_t gmax_o = take((size_t)NG * 256 * 4);
    size_t gcnt_o = take((size_t)NG * 4);
    size_t zero_bytes = o;
    size_t rp_o   = take((size_t)(N_NODES + 1) * 4);
    size_t cur_o  = take((size_t)N_NODES * 4);
    size_t bsum_o = take((size_t)64 * 4);
    size_t col_o  = take((size_t)E_TOT * 4);
    size_t ssrc_o = take((size_t)N_NODES * NH * 4);
    size_t sdst_o = take((size_t)N_NODES * NH * 4);
    size_t alp_o  = take((size_t)NH * E_TOT * 4);      // per-head alpha planes
    size_t hh_o   = take((size_t)N_NODES * 256 * 2);   // fp16 h slice-major (gather)
    size_t bufH_o = take((size_t)N_NODES * 256 * 2);   // fp16 h row-major (gemm/pool in)
    size_t wp0_o  = take((size_t)(8 + 1) * 4 * 64 * 8 * 2);   // packed W + score tile
    size_t wp1_o  = take((size_t)(16 + 1) * 4 * 64 * 8 * 2);
    size_t wp2_o  = take((size_t)(16 + 1) * 8 * 64 * 8 * 2);

    int*      cnt    = (int*)(ws + cnt_o);
    float*    gsum   = (float*)(ws + gsum_o);
    float*    gmax   = (float*)(ws + gmax_o);
    int*      gcnt   = (int*)(ws + gcnt_o);
    int*      row_ptr= (int*)(ws + rp_o);
    int*      cursor = (int*)(ws + cur_o);
    int*      bsum   = (int*)(ws + bsum_o);
    int*      col    = (int*)(ws + col_o);
    float*    ssrc   = (float*)(ws + ssrc_o);
    float*    sdst   = (float*)(ws + sdst_o);
    float*    alpha  = (float*)(ws + alp_o);
    _Float16* hH     = (_Float16*)(ws + hh_o);
    _Float16* bufH   = (_Float16*)(ws + bufH_o);
    _Float16* Wp0    = (_Float16*)(ws + wp0_o);
    _Float16* Wp1    = (_Float16*)(ws + wp1_o);
    _Float16* Wp2    = (_Float16*)(ws + wp2_o);

    (void)hipMemsetAsync(ws, 0, zero_bytes, stream);

    count_dst_k<<<(E_TOT + 255) / 256, 256, 0, stream>>>(ei, cnt);
    scan_sums_k<<<64, 256, 0, stream>>>(cnt, bsum);
    scan_off_k<<<1, 64, 0, stream>>>(bsum, row_ptr);
    scan_write_k<<<64, 256, 0, stream>>>(cnt, bsum, row_ptr, cursor);
    fill_k<<<(E_TOT + 255) / 256, 256, 0, stream>>>(ei, cursor, col);

    // weight packing + score-tile folds (tiny)
    pack_w_k<128, 128><<<8, 256, 0, stream>>>(W0, Wp0);
    pack_w_k<128, 256><<<16, 256, 0, stream>>>(W1, Wp1);
    pack_w_k<256, 256><<<32, 256, 0, stream>>>(W2, Wp2);
    pack_a_k<128, 128><<<1, 256, 0, stream>>>(W0, as0, ad0, Wp0);
    pack_a_k<128, 256><<<1, 256, 0, stream>>>(W1, as1, ad1, Wp1);
    pack_a_k<256, 256><<<2, 256, 0, stream>>>(W2, as2, ad2, Wp2);

    int gemm_grid  = (N_NODES + 63) / 64;
    int alpha_grid = (N_NODES + 3) / 4;
    int agg128_grid = 8 * ((N_NODES + 127) / 128);
    int agg256_grid = 8 * ((N_NODES + 63) / 64);

    // layer 0: 128 -> H4*Fo32 (128)
    gemm_k<128, 128, float><<<gemm_grid, 256, 0, stream>>>(x, Wp0, hH, ssrc, sdst);
    alpha_k<<<alpha_grid, 256, 0, stream>>>(ssrc, sdst, row_ptr, col, alpha);
    agg3_k<128, 16, 2><<<agg128_grid, 256, 0, stream>>>(hH, alpha, row_ptr, col, b0, bufH);

    // layer 1: 128 -> H4*Fo64 (256)
    gemm_k<128, 256, _Float16><<<gemm_grid, 256, 0, stream>>>(bufH, Wp1, hH, ssrc, sdst);
    alpha_k<<<alpha_grid, 256, 0, stream>>>(ssrc, sdst, row_ptr, col, alpha);
    agg3_k<256, 32, 4><<<agg256_grid, 256, 0, stream>>>(hH, alpha, row_ptr, col, b1, bufH);

    // layer 2: 256 -> H4*Fo64 (256)
    gemm_k<256, 256, _Float16><<<gemm_grid, 256, 0, stream>>>(bufH, Wp2, hH, ssrc, sdst);
    alpha_k<<<alpha_grid, 256, 0, stream>>>(ssrc, sdst, row_ptr, col, alpha);
    agg3_k<256, 32, 4><<<agg256_grid, 256, 0, stream>>>(hH, alpha, row_ptr, col, b2, bufH);

    // pooling + readout
    pool_k<<<(N_NODES + 31) / 32, 256, 0, stream>>>(bufH, batch, gsum, gmax);
    gcnt_k<<<1, 128, 0, stream>>>(batch, gcnt);
    readout_k<<<NG, 64, 0, stream>>>(gsum, gmax, gcnt, Wout, bout, out);
}